// Round 2
// baseline (552.221 us; speedup 1.0000x reference)
//
#include <hip/hip_runtime.h>

// ---------------------------------------------------------------------------
// Pipeline:
//  k_prep : wfc[512,64] -> wfcT[64,512]   (k-major, coalesced in fc k-loop)
//           w2[64,32,3] -> w2t[3,32,64]   (o-contiguous, lane-coalesced)
//  kA     : h[v] = mean_j relu(conv3_j(vp[nb1[v,:]]))               [V]
//  kB     : f1[v,o] = h[v-1]*w1[o,0]+h[v]*w1[o,1]+h[v+1]*w1[o,2]+b1 [V,32]
//  kC     : h2[v,c] = mean_j relu(conv3_j(f1[nb2[v,j],c]))          [V,32]
//  kD     : f2[v,o] = sum_{k,c} h2[v-1+k,c]*w2t[k,c,o] + b2[o]      [V,64]
//  kE     : out[v,:] = softmax(f2[v,:] @ wfcT + bfc)                [V,512]
//
// R5 change: kE de-pressurized. R4's kE had 16 float4 accumulators + 4
// float4 w-regs -> 192 VGPRs (VGPR_Count=48 granules) -> ~14 waves/CU
// (Occupancy 44%) -> VALUBusy 52%, 143us vs a 42us FMA floor. New kE:
// 256 threads / 16 vertices, each thread owns TWO outputs (float2), so
// acc = 16 float2 = 32 VGPR, w = 4 float2 = 8 VGPR (~64 total). wfcT is
// still read exactly once per block (L2 traffic unchanged at ~800MB);
// per-thread FMA halves, wave count doubles -> latency hiding restored.
// ---------------------------------------------------------------------------

__global__ __launch_bounds__(256) void k_prep(const float* __restrict__ wfc,
                                              const float* __restrict__ w2,
                                              float* __restrict__ wfcT,
                                              float* __restrict__ w2t) {
    int t = blockIdx.x * 256 + threadIdx.x;
    if (t < 512 * 64) {
        int k = t >> 9;
        int s = t & 511;
        wfcT[t] = wfc[s * 64 + k];
    } else {
        int i = t - 512 * 64;
        if (i < 64 * 32 * 3) {
            int o = i / 96;
            int r = i - o * 96;
            int c = r / 3;
            int k = r - c * 3;
            w2t[(k * 32 + c) * 64 + o] = w2[i];
        }
    }
}

// conv1 over neighbor axis: one 32-lane segment per vertex
__global__ __launch_bounds__(256) void kA(const float* __restrict__ vp,
                                          const int* __restrict__ nb1,
                                          const float* __restrict__ wv1,
                                          const float* __restrict__ bv1,
                                          float* __restrict__ h, int V) {
    int t = blockIdx.x * 256 + threadIdx.x;
    int v = t >> 5;
    int j = t & 31;
    if (v >= V) return;
    float g = vp[nb1[v * 32 + j]];
    float gm = __shfl_up(g, 1, 32);
    if (j == 0) gm = 0.0f;
    float gp = __shfl_down(g, 1, 32);
    if (j == 31) gp = 0.0f;
    float c = wv1[0] * gm + wv1[1] * g + wv1[2] * gp + bv1[0];
    c = fmaxf(c, 0.0f);
    #pragma unroll
    for (int off = 16; off; off >>= 1) c += __shfl_xor(c, off, 32);
    if (j == 0) h[v] = c * (1.0f / 32.0f);
}

// vertex-shift 3-tap mix into 32 channels
__global__ __launch_bounds__(256) void kB(const float* __restrict__ h,
                                          const float* __restrict__ w1,
                                          const float* __restrict__ b1,
                                          float* __restrict__ f1, int V) {
    int t = blockIdx.x * 256 + threadIdx.x;
    int v = t >> 5;
    int o = t & 31;
    if (v >= V) return;
    float hm = (v > 0) ? h[v - 1] : 0.0f;
    float h0 = h[v];
    float hp = (v + 1 < V) ? h[v + 1] : 0.0f;
    f1[v * 32 + o] = fmaf(hm, w1[o * 3 + 0],
                     fmaf(h0, w1[o * 3 + 1],
                     fmaf(hp, w1[o * 3 + 2], b1[o])));
}

// conv2: gather 32 neighbor rows (32 ch each) into LDS, 3-tap along j, mean
__global__ __launch_bounds__(256) void kC(const float* __restrict__ f1,
                                          const int* __restrict__ nb2,
                                          const float* __restrict__ wv2,
                                          const float* __restrict__ bv2,
                                          float* __restrict__ h2, int V) {
    __shared__ float lds[8 * 32 * 32];  // [vv][j][c], 32 KB
    int t = threadIdx.x;
    int vbase = blockIdx.x * 8;
    int j = t >> 3;        // 0..31
    int seg = t & 7;       // float4 segment within row
    #pragma unroll
    for (int vv = 0; vv < 8; ++vv) {
        int v = vbase + vv;
        float4 val = make_float4(0.f, 0.f, 0.f, 0.f);
        if (v < V) {
            int idx = nb2[v * 32 + j];
            val = *(const float4*)(f1 + (size_t)idx * 32 + seg * 4);
        }
        *(float4*)(lds + vv * 1024 + j * 32 + seg * 4) = val;
    }
    __syncthreads();
    int vv = t >> 5;       // 0..7
    int c = t & 31;
    int v = vbase + vv;
    const float* L = lds + vv * 1024;
    float w0 = wv2[0], w1_ = wv2[1], w2_ = wv2[2], b = bv2[0];
    float prev = 0.0f, cur = L[c];
    float s = 0.0f;
    #pragma unroll
    for (int jj = 0; jj < 32; ++jj) {
        float nxt = (jj < 31) ? L[(jj + 1) * 32 + c] : 0.0f;
        float cv = fmaf(w0, prev, fmaf(w1_, cur, fmaf(w2_, nxt, b)));
        s += fmaxf(cv, 0.0f);
        prev = cur;
        cur = nxt;
    }
    if (v < V) h2[v * 32 + c] = s * (1.0f / 32.0f);
}

// f2 einsum: 256 threads / 32 vertices per block. h2 halo tile [34][32]
// staged in LDS via float4 vector loads; inner loop reads h2 as conflict-
// free LDS broadcasts, w2t lane-coalesced from L1.
__global__ __launch_bounds__(256) void kD(const float* __restrict__ h2,
                                          const float* __restrict__ w2t,
                                          const float* __restrict__ b2,
                                          float* __restrict__ f2, int V) {
    __shared__ float tile[34 * 32];     // 4.25 KB, rows v0-1 .. v0+32
    int t = threadIdx.x;
    int v0 = blockIdx.x * 32;

    // stage h2 halo: 34 rows x 32 ch = 272 float4
    for (int i = t; i < 272; i += 256) {
        int r = i >> 3;                 // tile row (8 float4 per row)
        int s = i & 7;
        int v = v0 - 1 + r;
        float4 val = make_float4(0.f, 0.f, 0.f, 0.f);
        if (v >= 0 && v < V)
            val = *(const float4*)(h2 + (size_t)v * 32 + s * 4);
        *(float4*)(tile + r * 32 + s * 4) = val;
    }
    __syncthreads();

    int o = t & 63;                     // output channel = lane
    int w = t >> 6;                     // wave id 0..3
    int vb = w * 8;                     // this wave's first vertex (rel. v0)
    float bo = b2[o];
    float acc[8];
    #pragma unroll
    for (int m = 0; m < 8; ++m) acc[m] = bo;

    #pragma unroll
    for (int c4 = 0; c4 < 8; ++c4) {
        float4 hv[10];
        #pragma unroll
        for (int r = 0; r < 10; ++r)
            hv[r] = *(const float4*)(tile + (vb + r) * 32 + c4 * 4);
        #pragma unroll
        for (int k = 0; k < 3; ++k) {
            #pragma unroll
            for (int cc = 0; cc < 4; ++cc) {
                int c = c4 * 4 + cc;
                float wv = w2t[(k * 32 + c) * 64 + o];
                #pragma unroll
                for (int m = 0; m < 8; ++m) {
                    float hval = (cc == 0) ? hv[m + k].x :
                                 (cc == 1) ? hv[m + k].y :
                                 (cc == 2) ? hv[m + k].z : hv[m + k].w;
                    acc[m] = fmaf(hval, wv, acc[m]);
                }
            }
        }
    }
    #pragma unroll
    for (int m = 0; m < 8; ++m) {
        int v = v0 + vb + m;
        if (v < V) f2[(size_t)v * 64 + o] = acc[m];
    }
}

#define REP16(X) X(0) X(1) X(2) X(3) X(4) X(5) X(6) X(7) \
                 X(8) X(9) X(10) X(11) X(12) X(13) X(14) X(15)

// fc + softmax: 256 threads, 16 vertices/block, thread owns TWO consecutive
// outputs (float2). acc = 16 float2 = 32 VGPR (vs 64 in the float4 version)
// -> ~64 VGPR total -> ~32 waves/CU. wfcT still read once per block.
__global__ __launch_bounds__(256) void kE(const float* __restrict__ f2,
                                          const float* __restrict__ wfcT,
                                          const float* __restrict__ bfc,
                                          float* __restrict__ out, int V) {
    __shared__ float f2s[16 * 64];          // 4 KB
    __shared__ float redmax[4][16];
    __shared__ float redsum[4][16];
    int t = threadIdx.x;
    int wid = t >> 6, lane = t & 63;
    int vbase = blockIdx.x * 16;
    int nv = V - vbase; if (nv > 16) nv = 16;

    {   // stage f2 tile: 256 float4 = 16*64 floats, one per thread
        float4 val = make_float4(0.f, 0.f, 0.f, 0.f);
        if (t < nv * 16) val = ((const float4*)(f2 + (size_t)vbase * 64))[t];
        ((float4*)f2s)[t] = val;
    }
    __syncthreads();

    int s0 = t * 2;                          // this thread's 2 output columns
    float2 bv = *(const float2*)(bfc + s0);

#define KE_DECL(m) float2 A##m = bv;
    REP16(KE_DECL)
#undef KE_DECL

    for (int k = 0; k < 64; k += 4) {
        float2 w0 = *(const float2*)(wfcT + (k + 0) * 512 + s0);
        float2 w1 = *(const float2*)(wfcT + (k + 1) * 512 + s0);
        float2 w2 = *(const float2*)(wfcT + (k + 2) * 512 + s0);
        float2 w3 = *(const float2*)(wfcT + (k + 3) * 512 + s0);
#define KE_FMA(m) { \
        float4 f = *(const float4*)(f2s + m * 64 + k); \
        A##m.x = fmaf(f.x, w0.x, fmaf(f.y, w1.x, fmaf(f.z, w2.x, fmaf(f.w, w3.x, A##m.x)))); \
        A##m.y = fmaf(f.x, w0.y, fmaf(f.y, w1.y, fmaf(f.z, w2.y, fmaf(f.w, w3.y, A##m.y)))); }
        REP16(KE_FMA)
#undef KE_FMA
    }

    // softmax over 512 per vertex: wave-reduce then 4-wave combine via LDS
#define KE_MAX(m) { \
        float lm = fmaxf(A##m.x, A##m.y); \
        lm = fmaxf(lm, __shfl_xor(lm, 32)); \
        lm = fmaxf(lm, __shfl_xor(lm, 16)); \
        lm = fmaxf(lm, __shfl_xor(lm, 8)); \
        lm = fmaxf(lm, __shfl_xor(lm, 4)); \
        lm = fmaxf(lm, __shfl_xor(lm, 2)); \
        lm = fmaxf(lm, __shfl_xor(lm, 1)); \
        if (lane == 0) redmax[wid][m] = lm; }
    REP16(KE_MAX)
#undef KE_MAX
    __syncthreads();

#define KE_EXP(m) { \
        float gm = fmaxf(fmaxf(redmax[0][m], redmax[1][m]), \
                         fmaxf(redmax[2][m], redmax[3][m])); \
        A##m.x = __expf(A##m.x - gm); \
        A##m.y = __expf(A##m.y - gm); \
        float ls = A##m.x + A##m.y; \
        ls += __shfl_xor(ls, 32); \
        ls += __shfl_xor(ls, 16); \
        ls += __shfl_xor(ls, 8); \
        ls += __shfl_xor(ls, 4); \
        ls += __shfl_xor(ls, 2); \
        ls += __shfl_xor(ls, 1); \
        if (lane == 0) redsum[wid][m] = ls; }
    REP16(KE_EXP)
#undef KE_EXP
    __syncthreads();

#define KE_STORE(m) if (m < nv) { \
        float inv = 1.0f / ((redsum[0][m] + redsum[1][m]) + \
                            (redsum[2][m] + redsum[3][m])); \
        *(float2*)(out + (size_t)(vbase + m) * 512 + s0) = \
            make_float2(A##m.x * inv, A##m.y * inv); }
    REP16(KE_STORE)
#undef KE_STORE
}

extern "C" void kernel_launch(void* const* d_in, const int* in_sizes, int n_in,
                              void* d_out, int out_size, void* d_ws, size_t ws_size,
                              hipStream_t stream) {
    (void)n_in; (void)out_size; (void)ws_size;
    const float* vp  = (const float*)d_in[0];
    const int*   nb1 = (const int*)d_in[1];
    const int*   nb2 = (const int*)d_in[2];
    const float* wv1 = (const float*)d_in[3];
    const float* bv1 = (const float*)d_in[4];
    const float* w1  = (const float*)d_in[5];
    const float* b1  = (const float*)d_in[6];
    const float* wv2 = (const float*)d_in[7];
    const float* bv2 = (const float*)d_in[8];
    const float* w2  = (const float*)d_in[9];
    const float* b2  = (const float*)d_in[10];
    const float* wfc = (const float*)d_in[11];
    const float* bfc = (const float*)d_in[12];
    float* out = (float*)d_out;
    const int V = in_sizes[0];

    float* ws = (float*)d_ws;
    size_t off = 0;
    float* h    = ws + off; off += (size_t)V;
    float* f1   = ws + off; off += (size_t)V * 32;
    float* h2   = ws + off; off += (size_t)V * 32;
    float* f2   = ws + off; off += (size_t)V * 64;
    float* wfcT = ws + off; off += 512 * 64;
    float* w2t  = ws + off; off += 3 * 32 * 64;

    k_prep<<<(512 * 64 + 64 * 32 * 3 + 255) / 256, 256, 0, stream>>>(wfc, w2, wfcT, w2t);
    kA<<<(V * 32 + 255) / 256, 256, 0, stream>>>(vp, nb1, wv1, bv1, h, V);
    kB<<<(V * 32 + 255) / 256, 256, 0, stream>>>(h, w1, b1, f1, V);
    kC<<<(V + 7) / 8, 256, 0, stream>>>(f1, nb2, wv2, bv2, h2, V);
    kD<<<(V + 31) / 32, 256, 0, stream>>>(h2, w2t, b2, f2, V);
    kE<<<(V + 15) / 16, 256, 0, stream>>>(f2, wfcT, bfc, out, V);
}

// Round 3
// 505.496 us; speedup vs baseline: 1.0924x; 1.0924x over previous
//
#include <hip/hip_runtime.h>

// ---------------------------------------------------------------------------
// Pipeline:
//  k_prep : wfc[512,64] -> wfcT[64,512]   (k-major, coalesced in fc k-loop)
//           w2[64,32,3] -> w2t[3,32,64]   (o-contiguous, lane-coalesced)
//  kA     : h[v] = mean_j relu(conv3_j(vp[nb1[v,:]]))               [V]
//  kB     : f1[v,o] = h[v-1]*w1[o,0]+h[v]*w1[o,1]+h[v+1]*w1[o,2]+b1 [V,32]
//  kC     : h2[v,c] = mean_j relu(conv3_j(f1[nb2[v,j],c]))          [V,32]
//  kD     : f2[v,o] = sum_{k,c} h2[v-1+k,c]*w2t[k,c,o] + b2[o]      [V,64]
//  kE     : out[v,:] = softmax(f2[v,:] @ wfcT + bfc)                [V,512]
//
// R6 change: kE's f2 operand moved from LDS broadcasts to the SCALAR pipe.
// R4/R5 post-mortem: every KE_FMA did a wave-wide ds_read_b128 (1KB/wave)
// feeding only 16 FMA/lane -> 3.3GB (R4) / 6.6GB (R5) of LDS reads = 47/95us
// at the 69TB/s LDS ceiling. That, not VGPRs, was the kE bottleneck (R5's
// occupancy didn't move despite smaller accs; time rose with LDS volume).
// All f2s accesses are wave-UNIFORM (m,k,vbase uniform) -> read f2 rows
// directly from global with uniform addresses: hipcc selects s_load_dwordx4
// (f2 unwritten here, __restrict__), values land in SGPRs and feed v_fma as
// the 1-SGPR operand. Zero LDS + zero per-lane VMEM for f; 4KB/block via
// scalar cache. f2s tile + its barrier deleted; back to 128thr/float4 shape.
// ---------------------------------------------------------------------------

__global__ __launch_bounds__(256) void k_prep(const float* __restrict__ wfc,
                                              const float* __restrict__ w2,
                                              float* __restrict__ wfcT,
                                              float* __restrict__ w2t) {
    int t = blockIdx.x * 256 + threadIdx.x;
    if (t < 512 * 64) {
        int k = t >> 9;
        int s = t & 511;
        wfcT[t] = wfc[s * 64 + k];
    } else {
        int i = t - 512 * 64;
        if (i < 64 * 32 * 3) {
            int o = i / 96;
            int r = i - o * 96;
            int c = r / 3;
            int k = r - c * 3;
            w2t[(k * 32 + c) * 64 + o] = w2[i];
        }
    }
}

// conv1 over neighbor axis: one 32-lane segment per vertex
__global__ __launch_bounds__(256) void kA(const float* __restrict__ vp,
                                          const int* __restrict__ nb1,
                                          const float* __restrict__ wv1,
                                          const float* __restrict__ bv1,
                                          float* __restrict__ h, int V) {
    int t = blockIdx.x * 256 + threadIdx.x;
    int v = t >> 5;
    int j = t & 31;
    if (v >= V) return;
    float g = vp[nb1[v * 32 + j]];
    float gm = __shfl_up(g, 1, 32);
    if (j == 0) gm = 0.0f;
    float gp = __shfl_down(g, 1, 32);
    if (j == 31) gp = 0.0f;
    float c = wv1[0] * gm + wv1[1] * g + wv1[2] * gp + bv1[0];
    c = fmaxf(c, 0.0f);
    #pragma unroll
    for (int off = 16; off; off >>= 1) c += __shfl_xor(c, off, 32);
    if (j == 0) h[v] = c * (1.0f / 32.0f);
}

// vertex-shift 3-tap mix into 32 channels
__global__ __launch_bounds__(256) void kB(const float* __restrict__ h,
                                          const float* __restrict__ w1,
                                          const float* __restrict__ b1,
                                          float* __restrict__ f1, int V) {
    int t = blockIdx.x * 256 + threadIdx.x;
    int v = t >> 5;
    int o = t & 31;
    if (v >= V) return;
    float hm = (v > 0) ? h[v - 1] : 0.0f;
    float h0 = h[v];
    float hp = (v + 1 < V) ? h[v + 1] : 0.0f;
    f1[v * 32 + o] = fmaf(hm, w1[o * 3 + 0],
                     fmaf(h0, w1[o * 3 + 1],
                     fmaf(hp, w1[o * 3 + 2], b1[o])));
}

// conv2: gather 32 neighbor rows (32 ch each) into LDS, 3-tap along j, mean
__global__ __launch_bounds__(256) void kC(const float* __restrict__ f1,
                                          const int* __restrict__ nb2,
                                          const float* __restrict__ wv2,
                                          const float* __restrict__ bv2,
                                          float* __restrict__ h2, int V) {
    __shared__ float lds[8 * 32 * 32];  // [vv][j][c], 32 KB
    int t = threadIdx.x;
    int vbase = blockIdx.x * 8;
    int j = t >> 3;        // 0..31
    int seg = t & 7;       // float4 segment within row
    #pragma unroll
    for (int vv = 0; vv < 8; ++vv) {
        int v = vbase + vv;
        float4 val = make_float4(0.f, 0.f, 0.f, 0.f);
        if (v < V) {
            int idx = nb2[v * 32 + j];
            val = *(const float4*)(f1 + (size_t)idx * 32 + seg * 4);
        }
        *(float4*)(lds + vv * 1024 + j * 32 + seg * 4) = val;
    }
    __syncthreads();
    int vv = t >> 5;       // 0..7
    int c = t & 31;
    int v = vbase + vv;
    const float* L = lds + vv * 1024;
    float w0 = wv2[0], w1_ = wv2[1], w2_ = wv2[2], b = bv2[0];
    float prev = 0.0f, cur = L[c];
    float s = 0.0f;
    #pragma unroll
    for (int jj = 0; jj < 32; ++jj) {
        float nxt = (jj < 31) ? L[(jj + 1) * 32 + c] : 0.0f;
        float cv = fmaf(w0, prev, fmaf(w1_, cur, fmaf(w2_, nxt, b)));
        s += fmaxf(cv, 0.0f);
        prev = cur;
        cur = nxt;
    }
    if (v < V) h2[v * 32 + c] = s * (1.0f / 32.0f);
}

// f2 einsum: 256 threads / 32 vertices per block. h2 halo tile [34][32]
// staged in LDS via float4 vector loads; inner loop reads h2 as conflict-
// free LDS broadcasts, w2t lane-coalesced from L1.
__global__ __launch_bounds__(256) void kD(const float* __restrict__ h2,
                                          const float* __restrict__ w2t,
                                          const float* __restrict__ b2,
                                          float* __restrict__ f2, int V) {
    __shared__ float tile[34 * 32];     // 4.25 KB, rows v0-1 .. v0+32
    int t = threadIdx.x;
    int v0 = blockIdx.x * 32;

    // stage h2 halo: 34 rows x 32 ch = 272 float4
    for (int i = t; i < 272; i += 256) {
        int r = i >> 3;                 // tile row (8 float4 per row)
        int s = i & 7;
        int v = v0 - 1 + r;
        float4 val = make_float4(0.f, 0.f, 0.f, 0.f);
        if (v >= 0 && v < V)
            val = *(const float4*)(h2 + (size_t)v * 32 + s * 4);
        *(float4*)(tile + r * 32 + s * 4) = val;
    }
    __syncthreads();

    int o = t & 63;                     // output channel = lane
    int w = t >> 6;                     // wave id 0..3
    int vb = w * 8;                     // this wave's first vertex (rel. v0)
    float bo = b2[o];
    float acc[8];
    #pragma unroll
    for (int m = 0; m < 8; ++m) acc[m] = bo;

    #pragma unroll
    for (int c4 = 0; c4 < 8; ++c4) {
        float4 hv[10];
        #pragma unroll
        for (int r = 0; r < 10; ++r)
            hv[r] = *(const float4*)(tile + (vb + r) * 32 + c4 * 4);
        #pragma unroll
        for (int k = 0; k < 3; ++k) {
            #pragma unroll
            for (int cc = 0; cc < 4; ++cc) {
                int c = c4 * 4 + cc;
                float wv = w2t[(k * 32 + c) * 64 + o];
                #pragma unroll
                for (int m = 0; m < 8; ++m) {
                    float hval = (cc == 0) ? hv[m + k].x :
                                 (cc == 1) ? hv[m + k].y :
                                 (cc == 2) ? hv[m + k].z : hv[m + k].w;
                    acc[m] = fmaf(hval, wv, acc[m]);
                }
            }
        }
    }
    #pragma unroll
    for (int m = 0; m < 8; ++m) {
        int v = v0 + vb + m;
        if (v < V) f2[(size_t)v * 64 + o] = acc[m];
    }
}

#define REP16(X) X(0) X(1) X(2) X(3) X(4) X(5) X(6) X(7) \
                 X(8) X(9) X(10) X(11) X(12) X(13) X(14) X(15)

// fc + softmax: 128 threads, 16 vertices/block, thread owns 4 consecutive
// outputs (float4-coalesced wfcT loads). f2 operand read with wave-UNIFORM
// addresses straight from global -> scalar loads (SGPRs), no LDS tile.
__global__ __launch_bounds__(128) void kE(const float* __restrict__ f2,
                                          const float* __restrict__ wfcT,
                                          const float* __restrict__ bfc,
                                          float* __restrict__ out, int V) {
    __shared__ float redmax[2][16];
    __shared__ float redsum[2][16];
    int t = threadIdx.x;
    int wid = t >> 6, lane = t & 63;
    int vbase = blockIdx.x * 16;
    int nv = V - vbase; if (nv > 16) nv = 16;

    int s0 = t * 4;
    float4 bv = *(const float4*)(bfc + s0);

    // uniform (clamped) row pointers -> scalar-load friendly
#define KE_ROW(m) const float* fr##m = f2 + (size_t)(vbase + ((m) < nv ? (m) : 0)) * 64;
    REP16(KE_ROW)
#undef KE_ROW

#define KE_DECL(m) float4 A##m = bv;
    REP16(KE_DECL)
#undef KE_DECL

    for (int k = 0; k < 64; k += 4) {
        float4 w0 = *(const float4*)(wfcT + (k + 0) * 512 + s0);
        float4 w1 = *(const float4*)(wfcT + (k + 1) * 512 + s0);
        float4 w2 = *(const float4*)(wfcT + (k + 2) * 512 + s0);
        float4 w3 = *(const float4*)(wfcT + (k + 3) * 512 + s0);
#define KE_FMA(m) { \
        float4 f = *(const float4*)(fr##m + k); \
        A##m.x = fmaf(f.x, w0.x, fmaf(f.y, w1.x, fmaf(f.z, w2.x, fmaf(f.w, w3.x, A##m.x)))); \
        A##m.y = fmaf(f.x, w0.y, fmaf(f.y, w1.y, fmaf(f.z, w2.y, fmaf(f.w, w3.y, A##m.y)))); \
        A##m.z = fmaf(f.x, w0.z, fmaf(f.y, w1.z, fmaf(f.z, w2.z, fmaf(f.w, w3.z, A##m.z)))); \
        A##m.w = fmaf(f.x, w0.w, fmaf(f.y, w1.w, fmaf(f.z, w2.w, fmaf(f.w, w3.w, A##m.w)))); }
        REP16(KE_FMA)
#undef KE_FMA
    }

    // softmax over 512 per vertex: wave-reduce then 2-wave combine via LDS
#define KE_MAX(m) { \
        float lm = fmaxf(fmaxf(A##m.x, A##m.y), fmaxf(A##m.z, A##m.w)); \
        lm = fmaxf(lm, __shfl_xor(lm, 32)); \
        lm = fmaxf(lm, __shfl_xor(lm, 16)); \
        lm = fmaxf(lm, __shfl_xor(lm, 8)); \
        lm = fmaxf(lm, __shfl_xor(lm, 4)); \
        lm = fmaxf(lm, __shfl_xor(lm, 2)); \
        lm = fmaxf(lm, __shfl_xor(lm, 1)); \
        if (lane == 0) redmax[wid][m] = lm; }
    REP16(KE_MAX)
#undef KE_MAX
    __syncthreads();

#define KE_EXP(m) { \
        float gm = fmaxf(redmax[0][m], redmax[1][m]); \
        A##m.x = __expf(A##m.x - gm); \
        A##m.y = __expf(A##m.y - gm); \
        A##m.z = __expf(A##m.z - gm); \
        A##m.w = __expf(A##m.w - gm); \
        float ls = (A##m.x + A##m.y) + (A##m.z + A##m.w); \
        ls += __shfl_xor(ls, 32); \
        ls += __shfl_xor(ls, 16); \
        ls += __shfl_xor(ls, 8); \
        ls += __shfl_xor(ls, 4); \
        ls += __shfl_xor(ls, 2); \
        ls += __shfl_xor(ls, 1); \
        if (lane == 0) redsum[wid][m] = ls; }
    REP16(KE_EXP)
#undef KE_EXP
    __syncthreads();

#define KE_STORE(m) if (m < nv) { \
        float inv = 1.0f / (redsum[0][m] + redsum[1][m]); \
        *(float4*)(out + (size_t)(vbase + m) * 512 + s0) = \
            make_float4(A##m.x * inv, A##m.y * inv, A##m.z * inv, A##m.w * inv); }
    REP16(KE_STORE)
#undef KE_STORE
}

extern "C" void kernel_launch(void* const* d_in, const int* in_sizes, int n_in,
                              void* d_out, int out_size, void* d_ws, size_t ws_size,
                              hipStream_t stream) {
    (void)n_in; (void)out_size; (void)ws_size;
    const float* vp  = (const float*)d_in[0];
    const int*   nb1 = (const int*)d_in[1];
    const int*   nb2 = (const int*)d_in[2];
    const float* wv1 = (const float*)d_in[3];
    const float* bv1 = (const float*)d_in[4];
    const float* w1  = (const float*)d_in[5];
    const float* b1  = (const float*)d_in[6];
    const float* wv2 = (const float*)d_in[7];
    const float* bv2 = (const float*)d_in[8];
    const float* w2  = (const float*)d_in[9];
    const float* b2  = (const float*)d_in[10];
    const float* wfc = (const float*)d_in[11];
    const float* bfc = (const float*)d_in[12];
    float* out = (float*)d_out;
    const int V = in_sizes[0];

    float* ws = (float*)d_ws;
    size_t off = 0;
    float* h    = ws + off; off += (size_t)V;
    float* f1   = ws + off; off += (size_t)V * 32;
    float* h2   = ws + off; off += (size_t)V * 32;
    float* f2   = ws + off; off += (size_t)V * 64;
    float* wfcT = ws + off; off += 512 * 64;
    float* w2t  = ws + off; off += 3 * 32 * 64;

    k_prep<<<(512 * 64 + 64 * 32 * 3 + 255) / 256, 256, 0, stream>>>(wfc, w2, wfcT, w2t);
    kA<<<(V * 32 + 255) / 256, 256, 0, stream>>>(vp, nb1, wv1, bv1, h, V);
    kB<<<(V * 32 + 255) / 256, 256, 0, stream>>>(h, w1, b1, f1, V);
    kC<<<(V + 7) / 8, 256, 0, stream>>>(f1, nb2, wv2, bv2, h2, V);
    kD<<<(V + 31) / 32, 256, 0, stream>>>(h2, w2t, b2, f2, V);
    kE<<<(V + 15) / 16, 128, 0, stream>>>(f2, wfcT, bfc, out, V);
}

// Round 4
// 491.308 us; speedup vs baseline: 1.1240x; 1.0289x over previous
//
#include <hip/hip_runtime.h>

// ---------------------------------------------------------------------------
// Pipeline:
//  k_prep : wfc[512,64] -> wfcT[64,512]   (k-major, coalesced in fc k-loop)
//           w2[64,32,3] -> w2t[3,32,64]   (o-contiguous, lane-coalesced)
//  kA     : h[v] = mean_j relu(conv3_j(vp[nb1[v,:]]))               [V]
//  kB     : f1[v,o] = h[v-1]*w1[o,0]+h[v]*w1[o,1]+h[v+1]*w1[o,2]+b1 [V,32]
//  kC     : h2[v,c] = mean_j relu(conv3_j(f1[nb2[v,j],c]))          [V,32]
//  kD     : f2[v,o] = sum_{k,c} h2[v-1+k,c]*w2t[k,c,o] + b2[o]      [V,64]
//  kE     : out[v,:] = softmax(f2[v,:] @ wfcT + bfc)                [V,512]
//
// R7 changes (two occupancy-starved kernels, same disease):
//  kC: was 8 vertices / 32KB LDS -> 5 blocks/CU = 20 waves/CU; the random
//      f1 gather (~410MB of 128B rows) is latency-bound and the serial LDS
//      walk phase issues no gathers. Now 4 vertices / 16KB LDS -> 8 blocks
//      = 32 waves/CU (100%). j-walk split across half-waves (16 steps each),
//      combined with one __shfl_xor(s,32). Same total work.
//  kE: R1/R3 both sat ~135-144us with heavy float4 acc state (128thr);
//      R2 proved float2 accs alone don't help if you add LDS traffic.
//      Combine the two wins: 256thr + float2 accs (32 VGPR) + NO LDS tile;
//      f2 read via ONE uniform SGPR base (f2+vbase*64) with compile-time
//      immediate offsets m*64+k (<=4080B, folds into the 13-bit imm ->
//      zero address VALU). V%16==0 so no tail; reads stay in-workspace.
// ---------------------------------------------------------------------------

__global__ __launch_bounds__(256) void k_prep(const float* __restrict__ wfc,
                                              const float* __restrict__ w2,
                                              float* __restrict__ wfcT,
                                              float* __restrict__ w2t) {
    int t = blockIdx.x * 256 + threadIdx.x;
    if (t < 512 * 64) {
        int k = t >> 9;
        int s = t & 511;
        wfcT[t] = wfc[s * 64 + k];
    } else {
        int i = t - 512 * 64;
        if (i < 64 * 32 * 3) {
            int o = i / 96;
            int r = i - o * 96;
            int c = r / 3;
            int k = r - c * 3;
            w2t[(k * 32 + c) * 64 + o] = w2[i];
        }
    }
}

// conv1 over neighbor axis: one 32-lane segment per vertex
__global__ __launch_bounds__(256) void kA(const float* __restrict__ vp,
                                          const int* __restrict__ nb1,
                                          const float* __restrict__ wv1,
                                          const float* __restrict__ bv1,
                                          float* __restrict__ h, int V) {
    int t = blockIdx.x * 256 + threadIdx.x;
    int v = t >> 5;
    int j = t & 31;
    if (v >= V) return;
    float g = vp[nb1[v * 32 + j]];
    float gm = __shfl_up(g, 1, 32);
    if (j == 0) gm = 0.0f;
    float gp = __shfl_down(g, 1, 32);
    if (j == 31) gp = 0.0f;
    float c = wv1[0] * gm + wv1[1] * g + wv1[2] * gp + bv1[0];
    c = fmaxf(c, 0.0f);
    #pragma unroll
    for (int off = 16; off; off >>= 1) c += __shfl_xor(c, off, 32);
    if (j == 0) h[v] = c * (1.0f / 32.0f);
}

// vertex-shift 3-tap mix into 32 channels
__global__ __launch_bounds__(256) void kB(const float* __restrict__ h,
                                          const float* __restrict__ w1,
                                          const float* __restrict__ b1,
                                          float* __restrict__ f1, int V) {
    int t = blockIdx.x * 256 + threadIdx.x;
    int v = t >> 5;
    int o = t & 31;
    if (v >= V) return;
    float hm = (v > 0) ? h[v - 1] : 0.0f;
    float h0 = h[v];
    float hp = (v + 1 < V) ? h[v + 1] : 0.0f;
    f1[v * 32 + o] = fmaf(hm, w1[o * 3 + 0],
                     fmaf(h0, w1[o * 3 + 1],
                     fmaf(hp, w1[o * 3 + 2], b1[o])));
}

// conv2: gather 32 neighbor rows (32 ch each) into LDS, 3-tap along j, mean.
// 4 vertices / 16KB LDS / 256 thr -> 8 blocks/CU = 32 waves/CU.
__global__ __launch_bounds__(256) void kC(const float* __restrict__ f1,
                                          const int* __restrict__ nb2,
                                          const float* __restrict__ wv2,
                                          const float* __restrict__ bv2,
                                          float* __restrict__ h2, int V) {
    __shared__ float lds[4 * 32 * 32];  // [vv][j][c], 16 KB
    int t = threadIdx.x;
    int vbase = blockIdx.x * 4;
    int j = (t >> 3) & 31;   // row within a vertex's neighbor list
    int seg = t & 7;         // float4 segment within row

    // all 4 idx loads, then all 4 gathers, then all 4 LDS writes (MLP)
    int i0 = (vbase + 0 < V) ? nb2[(vbase + 0) * 32 + j] : 0;
    int i1 = (vbase + 1 < V) ? nb2[(vbase + 1) * 32 + j] : 0;
    int i2 = (vbase + 2 < V) ? nb2[(vbase + 2) * 32 + j] : 0;
    int i3 = (vbase + 3 < V) ? nb2[(vbase + 3) * 32 + j] : 0;
    float4 z = make_float4(0.f, 0.f, 0.f, 0.f);
    float4 a0 = (vbase + 0 < V) ? *(const float4*)(f1 + (size_t)i0 * 32 + seg * 4) : z;
    float4 a1 = (vbase + 1 < V) ? *(const float4*)(f1 + (size_t)i1 * 32 + seg * 4) : z;
    float4 a2 = (vbase + 2 < V) ? *(const float4*)(f1 + (size_t)i2 * 32 + seg * 4) : z;
    float4 a3 = (vbase + 3 < V) ? *(const float4*)(f1 + (size_t)i3 * 32 + seg * 4) : z;
    *(float4*)(lds + 0 * 1024 + j * 32 + seg * 4) = a0;
    *(float4*)(lds + 1 * 1024 + j * 32 + seg * 4) = a1;
    *(float4*)(lds + 2 * 1024 + j * 32 + seg * 4) = a2;
    *(float4*)(lds + 3 * 1024 + j * 32 + seg * 4) = a3;
    __syncthreads();

    int vv   = t >> 6;        // 0..3 (one vertex per wave)
    int half = (t >> 5) & 1;  // lane bit 5: which 16-step half of the j-walk
    int c    = t & 31;
    int v = vbase + vv;
    const float* L = lds + vv * 1024;
    float w0 = wv2[0], w1_ = wv2[1], w2_ = wv2[2], b = bv2[0];
    int j0 = half * 16;
    float prev = half ? L[15 * 32 + c] : 0.0f;
    float cur  = L[j0 * 32 + c];
    float s = 0.0f;
    #pragma unroll
    for (int q = 0; q < 16; ++q) {
        int jj = j0 + q;
        float nxt = (jj < 31) ? L[(jj + 1) * 32 + c] : 0.0f;
        float cv = fmaf(w0, prev, fmaf(w1_, cur, fmaf(w2_, nxt, b)));
        s += fmaxf(cv, 0.0f);
        prev = cur;
        cur = nxt;
    }
    s += __shfl_xor(s, 32);   // combine the two 16-step halves
    if (half == 0 && v < V) h2[v * 32 + c] = s * (1.0f / 32.0f);
}

// f2 einsum: 256 threads / 32 vertices per block. h2 halo tile [34][32]
// staged in LDS via float4 vector loads; inner loop reads h2 as conflict-
// free LDS broadcasts, w2t lane-coalesced from L1.
__global__ __launch_bounds__(256) void kD(const float* __restrict__ h2,
                                          const float* __restrict__ w2t,
                                          const float* __restrict__ b2,
                                          float* __restrict__ f2, int V) {
    __shared__ float tile[34 * 32];     // 4.25 KB, rows v0-1 .. v0+32
    int t = threadIdx.x;
    int v0 = blockIdx.x * 32;

    // stage h2 halo: 34 rows x 32 ch = 272 float4
    for (int i = t; i < 272; i += 256) {
        int r = i >> 3;                 // tile row (8 float4 per row)
        int s = i & 7;
        int v = v0 - 1 + r;
        float4 val = make_float4(0.f, 0.f, 0.f, 0.f);
        if (v >= 0 && v < V)
            val = *(const float4*)(h2 + (size_t)v * 32 + s * 4);
        *(float4*)(tile + r * 32 + s * 4) = val;
    }
    __syncthreads();

    int o = t & 63;                     // output channel = lane
    int w = t >> 6;                     // wave id 0..3
    int vb = w * 8;                     // this wave's first vertex (rel. v0)
    float bo = b2[o];
    float acc[8];
    #pragma unroll
    for (int m = 0; m < 8; ++m) acc[m] = bo;

    #pragma unroll
    for (int c4 = 0; c4 < 8; ++c4) {
        float4 hv[10];
        #pragma unroll
        for (int r = 0; r < 10; ++r)
            hv[r] = *(const float4*)(tile + (vb + r) * 32 + c4 * 4);
        #pragma unroll
        for (int k = 0; k < 3; ++k) {
            #pragma unroll
            for (int cc = 0; cc < 4; ++cc) {
                int c = c4 * 4 + cc;
                float wv = w2t[(k * 32 + c) * 64 + o];
                #pragma unroll
                for (int m = 0; m < 8; ++m) {
                    float hval = (cc == 0) ? hv[m + k].x :
                                 (cc == 1) ? hv[m + k].y :
                                 (cc == 2) ? hv[m + k].z : hv[m + k].w;
                    acc[m] = fmaf(hval, wv, acc[m]);
                }
            }
        }
    }
    #pragma unroll
    for (int m = 0; m < 8; ++m) {
        int v = v0 + vb + m;
        if (v < V) f2[(size_t)v * 64 + o] = acc[m];
    }
}

#define REP16(X) X(0) X(1) X(2) X(3) X(4) X(5) X(6) X(7) \
                 X(8) X(9) X(10) X(11) X(12) X(13) X(14) X(15)

// fc + softmax: 256 threads, 16 vertices/block, thread owns TWO consecutive
// outputs (float2 accs = 32 VGPR). No LDS tile: f2 read via ONE uniform
// SGPR base + compile-time immediate offsets (m*64+k)*4 <= 4080B.
// Note: loads are unguarded for m>=nv; V%16==0 in this harness and any
// overread stays inside the workspace (wfcT follows f2), results unused.
__global__ __launch_bounds__(256) void kE(const float* __restrict__ f2,
                                          const float* __restrict__ wfcT,
                                          const float* __restrict__ bfc,
                                          float* __restrict__ out, int V) {
    __shared__ float redmax[4][16];
    __shared__ float redsum[4][16];
    int t = threadIdx.x;
    int wid = t >> 6, lane = t & 63;
    int vbase = blockIdx.x * 16;
    int nv = V - vbase; if (nv > 16) nv = 16;

    const float* fb = f2 + (size_t)vbase * 64;   // uniform base -> SGPRs

    int s0 = t * 2;                          // this thread's 2 output columns
    float2 bv = *(const float2*)(bfc + s0);

#define KE_DECL(m) float2 A##m = bv;
    REP16(KE_DECL)
#undef KE_DECL

    for (int k = 0; k < 64; k += 4) {
        float2 w0 = *(const float2*)(wfcT + (k + 0) * 512 + s0);
        float2 w1 = *(const float2*)(wfcT + (k + 1) * 512 + s0);
        float2 w2 = *(const float2*)(wfcT + (k + 2) * 512 + s0);
        float2 w3 = *(const float2*)(wfcT + (k + 3) * 512 + s0);
#define KE_FMA(m) { \
        float4 f = *(const float4*)(fb + m * 64 + k); \
        A##m.x = fmaf(f.x, w0.x, fmaf(f.y, w1.x, fmaf(f.z, w2.x, fmaf(f.w, w3.x, A##m.x)))); \
        A##m.y = fmaf(f.x, w0.y, fmaf(f.y, w1.y, fmaf(f.z, w2.y, fmaf(f.w, w3.y, A##m.y)))); }
        REP16(KE_FMA)
#undef KE_FMA
    }

    // softmax over 512 per vertex: wave-reduce then 4-wave combine via LDS
#define KE_MAX(m) { \
        float lm = fmaxf(A##m.x, A##m.y); \
        lm = fmaxf(lm, __shfl_xor(lm, 32)); \
        lm = fmaxf(lm, __shfl_xor(lm, 16)); \
        lm = fmaxf(lm, __shfl_xor(lm, 8)); \
        lm = fmaxf(lm, __shfl_xor(lm, 4)); \
        lm = fmaxf(lm, __shfl_xor(lm, 2)); \
        lm = fmaxf(lm, __shfl_xor(lm, 1)); \
        if (lane == 0) redmax[wid][m] = lm; }
    REP16(KE_MAX)
#undef KE_MAX
    __syncthreads();

#define KE_EXP(m) { \
        float gm = fmaxf(fmaxf(redmax[0][m], redmax[1][m]), \
                         fmaxf(redmax[2][m], redmax[3][m])); \
        A##m.x = __expf(A##m.x - gm); \
        A##m.y = __expf(A##m.y - gm); \
        float ls = A##m.x + A##m.y; \
        ls += __shfl_xor(ls, 32); \
        ls += __shfl_xor(ls, 16); \
        ls += __shfl_xor(ls, 8); \
        ls += __shfl_xor(ls, 4); \
        ls += __shfl_xor(ls, 2); \
        ls += __shfl_xor(ls, 1); \
        if (lane == 0) redsum[wid][m] = ls; }
    REP16(KE_EXP)
#undef KE_EXP
    __syncthreads();

#define KE_STORE(m) if (m < nv) { \
        float inv = 1.0f / ((redsum[0][m] + redsum[1][m]) + \
                            (redsum[2][m] + redsum[3][m])); \
        *(float2*)(out + (size_t)(vbase + m) * 512 + s0) = \
            make_float2(A##m.x * inv, A##m.y * inv); }
    REP16(KE_STORE)
#undef KE_STORE
}

extern "C" void kernel_launch(void* const* d_in, const int* in_sizes, int n_in,
                              void* d_out, int out_size, void* d_ws, size_t ws_size,
                              hipStream_t stream) {
    (void)n_in; (void)out_size; (void)ws_size;
    const float* vp  = (const float*)d_in[0];
    const int*   nb1 = (const int*)d_in[1];
    const int*   nb2 = (const int*)d_in[2];
    const float* wv1 = (const float*)d_in[3];
    const float* bv1 = (const float*)d_in[4];
    const float* w1  = (const float*)d_in[5];
    const float* b1  = (const float*)d_in[6];
    const float* wv2 = (const float*)d_in[7];
    const float* bv2 = (const float*)d_in[8];
    const float* w2  = (const float*)d_in[9];
    const float* b2  = (const float*)d_in[10];
    const float* wfc = (const float*)d_in[11];
    const float* bfc = (const float*)d_in[12];
    float* out = (float*)d_out;
    const int V = in_sizes[0];

    float* ws = (float*)d_ws;
    size_t off = 0;
    float* h    = ws + off; off += (size_t)V;
    float* f1   = ws + off; off += (size_t)V * 32;
    float* h2   = ws + off; off += (size_t)V * 32;
    float* f2   = ws + off; off += (size_t)V * 64;
    float* wfcT = ws + off; off += 512 * 64;
    float* w2t  = ws + off; off += 3 * 32 * 64;

    k_prep<<<(512 * 64 + 64 * 32 * 3 + 255) / 256, 256, 0, stream>>>(wfc, w2, wfcT, w2t);
    kA<<<(V * 32 + 255) / 256, 256, 0, stream>>>(vp, nb1, wv1, bv1, h, V);
    kB<<<(V * 32 + 255) / 256, 256, 0, stream>>>(h, w1, b1, f1, V);
    kC<<<(V + 3) / 4, 256, 0, stream>>>(f1, nb2, wv2, bv2, h2, V);
    kD<<<(V + 31) / 32, 256, 0, stream>>>(h2, w2t, b2, f2, V);
    kE<<<(V + 15) / 16, 256, 0, stream>>>(f2, wfcT, bfc, out, V);
}

// Round 6
// 449.774 us; speedup vs baseline: 1.2278x; 1.0923x over previous
//
#include <hip/hip_runtime.h>

// ---------------------------------------------------------------------------
// Pipeline:
//  k_prep : wfc[512,64] -> wfcT[64,512]   (k-major, coalesced in fc k-loop)
//           w2[64,32,3] -> w2t[3,32,64]   (o-contiguous, lane-coalesced)
//  kA     : h[v] = mean_j relu(conv3_j(vp[nb1[v,:]]))               [V]
//  kB     : f1[v,o] = h[v-1]*w1[o,0]+h[v]*w1[o,1]+h[v+1]*w1[o,2]+b1 [V,32]
//  kC     : h2[v,c] = mean_j relu(conv3_j(f1[nb2[v,j],c]))          [V,32]
//  kD     : f2[v,o] = sum_{k,c} h2[v-1+k,c]*w2t[k,c,o] + b2[o]      [V,64]
//  kE     : out[v,:] = softmax(f2[v,:] @ wfcT + bfc)                [V,512]
//
// R9 = R8 with the compile fix: __builtin_nontemporal_store requires a
// NATIVE vector type, not HIP's float2 class -> use ext_vector_type(2).
// R8 changes (unchanged, still untested):
//  kC: R7's warmup dispatch showed Occupancy 6.5% / VALUBusy 3.5% -- ~2
//      waves/CU resident vs the 32 the static limits allow; gather latency
//      fully exposed. Rewrite BARRIER-FREE: one wave per vertex, lane =
//      (j-half, c). Each lane loads 16 x[j,c] from its half's 16 random
//      neighbor rows -- 16 independent loads = 16-deep MLP/wave, no LDS,
//      no __syncthreads. Conv boundary via two __shfl_xor(..,32).
//  kE: R5 ran at 224 VGPR -> 41% occupancy. __launch_bounds__(256,5).
//  out: nontemporal stores (200MB write-only stream).
// ---------------------------------------------------------------------------

typedef float f32x2 __attribute__((ext_vector_type(2)));

__global__ __launch_bounds__(256) void k_prep(const float* __restrict__ wfc,
                                              const float* __restrict__ w2,
                                              float* __restrict__ wfcT,
                                              float* __restrict__ w2t) {
    int t = blockIdx.x * 256 + threadIdx.x;
    if (t < 512 * 64) {
        int k = t >> 9;
        int s = t & 511;
        wfcT[t] = wfc[s * 64 + k];
    } else {
        int i = t - 512 * 64;
        if (i < 64 * 32 * 3) {
            int o = i / 96;
            int r = i - o * 96;
            int c = r / 3;
            int k = r - c * 3;
            w2t[(k * 32 + c) * 64 + o] = w2[i];
        }
    }
}

// conv1 over neighbor axis: one 32-lane segment per vertex
__global__ __launch_bounds__(256) void kA(const float* __restrict__ vp,
                                          const int* __restrict__ nb1,
                                          const float* __restrict__ wv1,
                                          const float* __restrict__ bv1,
                                          float* __restrict__ h, int V) {
    int t = blockIdx.x * 256 + threadIdx.x;
    int v = t >> 5;
    int j = t & 31;
    if (v >= V) return;
    float g = vp[nb1[v * 32 + j]];
    float gm = __shfl_up(g, 1, 32);
    if (j == 0) gm = 0.0f;
    float gp = __shfl_down(g, 1, 32);
    if (j == 31) gp = 0.0f;
    float c = wv1[0] * gm + wv1[1] * g + wv1[2] * gp + bv1[0];
    c = fmaxf(c, 0.0f);
    #pragma unroll
    for (int off = 16; off; off >>= 1) c += __shfl_xor(c, off, 32);
    if (j == 0) h[v] = c * (1.0f / 32.0f);
}

// vertex-shift 3-tap mix into 32 channels
__global__ __launch_bounds__(256) void kB(const float* __restrict__ h,
                                          const float* __restrict__ w1,
                                          const float* __restrict__ b1,
                                          float* __restrict__ f1, int V) {
    int t = blockIdx.x * 256 + threadIdx.x;
    int v = t >> 5;
    int o = t & 31;
    if (v >= V) return;
    float hm = (v > 0) ? h[v - 1] : 0.0f;
    float h0 = h[v];
    float hp = (v + 1 < V) ? h[v + 1] : 0.0f;
    f1[v * 32 + o] = fmaf(hm, w1[o * 3 + 0],
                     fmaf(h0, w1[o * 3 + 1],
                     fmaf(hp, w1[o * 3 + 2], b1[o])));
}

// conv2: one WAVE per vertex, barrier-free. lane = (half h, channel c).
// Each lane loads x[j,c] for its half's 16 j's: per load instr the 32
// lanes of a half read one full 128B f1 row -> 2 lines/instr, 16
// independent instrs = 16-deep MLP. Conv boundary j=15/16 via shfl_xor.
__global__ __launch_bounds__(256) void kC(const float* __restrict__ f1,
                                          const int* __restrict__ nb2,
                                          const float* __restrict__ wv2,
                                          const float* __restrict__ bv2,
                                          float* __restrict__ h2, int V) {
    int t = threadIdx.x;
    int v = blockIdx.x * 4 + (t >> 6);
    if (v >= V) return;
    int hf = (t >> 5) & 1;   // which 16-j half
    int c  = t & 31;         // channel
    const int* nb = nb2 + (size_t)v * 32 + hf * 16;

    float x[16];
    #pragma unroll
    for (int q = 0; q < 16; ++q) {
        int idx = nb[q];
        x[q] = f1[(size_t)idx * 32 + c];
    }

    float w0 = wv2[0], w1_ = wv2[1], w2_ = wv2[2], b = bv2[0];
    float ox0  = __shfl_xor(x[0], 32);    // other half's x[0]
    float ox15 = __shfl_xor(x[15], 32);   // other half's x[15]
    float prevq0  = hf ? ox15 : 0.0f;     // g[j-1] at q=0  (g[-1]=0)
    float nextq15 = hf ? 0.0f : ox0;      // g[j+1] at q=15 (g[32]=0)

    float s = 0.0f;
    #pragma unroll
    for (int q = 0; q < 16; ++q) {
        float pv = (q == 0)  ? prevq0  : x[q - 1];
        float nx = (q == 15) ? nextq15 : x[q + 1];
        float cv = fmaf(w0, pv, fmaf(w1_, x[q], fmaf(w2_, nx, b)));
        s += fmaxf(cv, 0.0f);
    }
    s += __shfl_xor(s, 32);   // combine the two 16-j halves
    if (hf == 0) h2[(size_t)v * 32 + c] = s * (1.0f / 32.0f);
}

// f2 einsum: 256 threads / 32 vertices per block. h2 halo tile [34][32]
// staged in LDS via float4 vector loads; inner loop reads h2 as conflict-
// free LDS broadcasts, w2t lane-coalesced from L1.
__global__ __launch_bounds__(256) void kD(const float* __restrict__ h2,
                                          const float* __restrict__ w2t,
                                          const float* __restrict__ b2,
                                          float* __restrict__ f2, int V) {
    __shared__ float tile[34 * 32];     // 4.25 KB, rows v0-1 .. v0+32
    int t = threadIdx.x;
    int v0 = blockIdx.x * 32;

    // stage h2 halo: 34 rows x 32 ch = 272 float4
    for (int i = t; i < 272; i += 256) {
        int r = i >> 3;                 // tile row (8 float4 per row)
        int s = i & 7;
        int v = v0 - 1 + r;
        float4 val = make_float4(0.f, 0.f, 0.f, 0.f);
        if (v >= 0 && v < V)
            val = *(const float4*)(h2 + (size_t)v * 32 + s * 4);
        *(float4*)(tile + r * 32 + s * 4) = val;
    }
    __syncthreads();

    int o = t & 63;                     // output channel = lane
    int w = t >> 6;                     // wave id 0..3
    int vb = w * 8;                     // this wave's first vertex (rel. v0)
    float bo = b2[o];
    float acc[8];
    #pragma unroll
    for (int m = 0; m < 8; ++m) acc[m] = bo;

    #pragma unroll
    for (int c4 = 0; c4 < 8; ++c4) {
        float4 hv[10];
        #pragma unroll
        for (int r = 0; r < 10; ++r)
            hv[r] = *(const float4*)(tile + (vb + r) * 32 + c4 * 4);
        #pragma unroll
        for (int k = 0; k < 3; ++k) {
            #pragma unroll
            for (int cc = 0; cc < 4; ++cc) {
                int c = c4 * 4 + cc;
                float wv = w2t[(k * 32 + c) * 64 + o];
                #pragma unroll
                for (int m = 0; m < 8; ++m) {
                    float hval = (cc == 0) ? hv[m + k].x :
                                 (cc == 1) ? hv[m + k].y :
                                 (cc == 2) ? hv[m + k].z : hv[m + k].w;
                    acc[m] = fmaf(hval, wv, acc[m]);
                }
            }
        }
    }
    #pragma unroll
    for (int m = 0; m < 8; ++m) {
        int v = v0 + vb + m;
        if (v < V) f2[(size_t)v * 64 + o] = acc[m];
    }
}

#define REP16(X) X(0) X(1) X(2) X(3) X(4) X(5) X(6) X(7) \
                 X(8) X(9) X(10) X(11) X(12) X(13) X(14) X(15)

// fc + softmax: 256 threads, 16 vertices/block, thread owns TWO consecutive
// outputs (float2 accs). No LDS tile: f2 read via ONE uniform SGPR base +
// compile-time immediate offsets. launch_bounds(256,5) caps VGPR ~100
// (was 224 unbounded -> 41% occupancy). out stored nontemporal (200MB
// write-only; keep it out of L2).
__global__ __launch_bounds__(256, 5) void kE(const float* __restrict__ f2,
                                             const float* __restrict__ wfcT,
                                             const float* __restrict__ bfc,
                                             float* __restrict__ out, int V) {
    __shared__ float redmax[4][16];
    __shared__ float redsum[4][16];
    int t = threadIdx.x;
    int wid = t >> 6, lane = t & 63;
    int vbase = blockIdx.x * 16;
    int nv = V - vbase; if (nv > 16) nv = 16;

    const float* fb = f2 + (size_t)vbase * 64;   // uniform base -> SGPRs

    int s0 = t * 2;                          // this thread's 2 output columns
    float2 bv = *(const float2*)(bfc + s0);

#define KE_DECL(m) float2 A##m = bv;
    REP16(KE_DECL)
#undef KE_DECL

    for (int k = 0; k < 64; k += 4) {
        float2 w0 = *(const float2*)(wfcT + (k + 0) * 512 + s0);
        float2 w1 = *(const float2*)(wfcT + (k + 1) * 512 + s0);
        float2 w2 = *(const float2*)(wfcT + (k + 2) * 512 + s0);
        float2 w3 = *(const float2*)(wfcT + (k + 3) * 512 + s0);
#define KE_FMA(m) { \
        float4 f = *(const float4*)(fb + m * 64 + k); \
        A##m.x = fmaf(f.x, w0.x, fmaf(f.y, w1.x, fmaf(f.z, w2.x, fmaf(f.w, w3.x, A##m.x)))); \
        A##m.y = fmaf(f.x, w0.y, fmaf(f.y, w1.y, fmaf(f.z, w2.y, fmaf(f.w, w3.y, A##m.y)))); }
        REP16(KE_FMA)
#undef KE_FMA
    }

    // softmax over 512 per vertex: wave-reduce then 4-wave combine via LDS
#define KE_MAX(m) { \
        float lm = fmaxf(A##m.x, A##m.y); \
        lm = fmaxf(lm, __shfl_xor(lm, 32)); \
        lm = fmaxf(lm, __shfl_xor(lm, 16)); \
        lm = fmaxf(lm, __shfl_xor(lm, 8)); \
        lm = fmaxf(lm, __shfl_xor(lm, 4)); \
        lm = fmaxf(lm, __shfl_xor(lm, 2)); \
        lm = fmaxf(lm, __shfl_xor(lm, 1)); \
        if (lane == 0) redmax[wid][m] = lm; }
    REP16(KE_MAX)
#undef KE_MAX
    __syncthreads();

#define KE_EXP(m) { \
        float gm = fmaxf(fmaxf(redmax[0][m], redmax[1][m]), \
                         fmaxf(redmax[2][m], redmax[3][m])); \
        A##m.x = __expf(A##m.x - gm); \
        A##m.y = __expf(A##m.y - gm); \
        float ls = A##m.x + A##m.y; \
        ls += __shfl_xor(ls, 32); \
        ls += __shfl_xor(ls, 16); \
        ls += __shfl_xor(ls, 8); \
        ls += __shfl_xor(ls, 4); \
        ls += __shfl_xor(ls, 2); \
        ls += __shfl_xor(ls, 1); \
        if (lane == 0) redsum[wid][m] = ls; }
    REP16(KE_EXP)
#undef KE_EXP
    __syncthreads();

#define KE_STORE(m) if (m < nv) { \
        float inv = 1.0f / ((redsum[0][m] + redsum[1][m]) + \
                            (redsum[2][m] + redsum[3][m])); \
        f32x2 r; r.x = A##m.x * inv; r.y = A##m.y * inv; \
        __builtin_nontemporal_store(r, \
            (f32x2*)(out + (size_t)(vbase + m) * 512 + s0)); }
    REP16(KE_STORE)
#undef KE_STORE
}

extern "C" void kernel_launch(void* const* d_in, const int* in_sizes, int n_in,
                              void* d_out, int out_size, void* d_ws, size_t ws_size,
                              hipStream_t stream) {
    (void)n_in; (void)out_size; (void)ws_size;
    const float* vp  = (const float*)d_in[0];
    const int*   nb1 = (const int*)d_in[1];
    const int*   nb2 = (const int*)d_in[2];
    const float* wv1 = (const float*)d_in[3];
    const float* bv1 = (const float*)d_in[4];
    const float* w1  = (const float*)d_in[5];
    const float* b1  = (const float*)d_in[6];
    const float* wv2 = (const float*)d_in[7];
    const float* bv2 = (const float*)d_in[8];
    const float* w2  = (const float*)d_in[9];
    const float* b2  = (const float*)d_in[10];
    const float* wfc = (const float*)d_in[11];
    const float* bfc = (const float*)d_in[12];
    float* out = (float*)d_out;
    const int V = in_sizes[0];

    float* ws = (float*)d_ws;
    size_t off = 0;
    float* h    = ws + off; off += (size_t)V;
    float* f1   = ws + off; off += (size_t)V * 32;
    float* h2   = ws + off; off += (size_t)V * 32;
    float* f2   = ws + off; off += (size_t)V * 64;
    float* wfcT = ws + off; off += 512 * 64;
    float* w2t  = ws + off; off += 3 * 32 * 64;

    k_prep<<<(512 * 64 + 64 * 32 * 3 + 255) / 256, 256, 0, stream>>>(wfc, w2, wfcT, w2t);
    kA<<<(V * 32 + 255) / 256, 256, 0, stream>>>(vp, nb1, wv1, bv1, h, V);
    kB<<<(V * 32 + 255) / 256, 256, 0, stream>>>(h, w1, b1, f1, V);
    kC<<<(V + 3) / 4, 256, 0, stream>>>(f1, nb2, wv2, bv2, h2, V);
    kD<<<(V + 31) / 32, 256, 0, stream>>>(h2, w2t, b2, f2, V);
    kE<<<(V + 15) / 16, 256, 0, stream>>>(f2, wfcT, bfc, out, V);
}

// Round 7
// 447.238 us; speedup vs baseline: 1.2347x; 1.0057x over previous
//
#include <hip/hip_runtime.h>

// ---------------------------------------------------------------------------
// Pipeline:
//  k_prep : wfc[512,64] -> wfcT[64,512]   (k-major, coalesced in fc k-loop)
//           w2[64,32,3] -> w2t[3,32,64]   (o-contiguous, lane-coalesced)
//  kA     : h[v] = mean_j relu(conv3_j(vp[nb1[v,:]]))               [V]
//  kB     : f1[v,o] = h[v-1]*w1[o,0]+h[v]*w1[o,1]+h[v+1]*w1[o,2]+b1 [V,32]
//  kC     : h2[v,c] = mean_j relu(conv3_j(f1[nb2[v,j],c]))          [V,32]
//  kD     : f2[v,o] = sum_{k,c} h2[v-1+k,c]*w2t[k,c,o] + b2[o]      [V,64]
//  kE     : out[v,:] = softmax(f2[v,:] @ wfcT + bfc)                [V,512]
//
// R10 changes:
//  kC: 2 vertices per WAVE (one per 32-lane half), lane = channel. Each
//      lane loads all 32 x[j] for its channel -> 32 independent gathers in
//      flight (was 16), conv fully lane-local (no shfl, no boundary fixup),
//      V%8==0 so no tail. ~48 VGPR -> 32 waves/CU. Doubles per-CU
//      outstanding loads on the latency-bound f1 gather.
//  kE: R6 hit exactly the requested 5 waves/SIMD (96 VGPR, 66% occ) and
//      s_load chains still stall 32% of cycles. (256,6) (cap ~85 VGPR,
//      24 waves/CU) + 8-wide k-step: batch 8 w-loads + 32B f s_loads per
//      iter -> longer independent scheduling window, fewer stall points.
// ---------------------------------------------------------------------------

typedef float f32x2 __attribute__((ext_vector_type(2)));

__global__ __launch_bounds__(256) void k_prep(const float* __restrict__ wfc,
                                              const float* __restrict__ w2,
                                              float* __restrict__ wfcT,
                                              float* __restrict__ w2t) {
    int t = blockIdx.x * 256 + threadIdx.x;
    if (t < 512 * 64) {
        int k = t >> 9;
        int s = t & 511;
        wfcT[t] = wfc[s * 64 + k];
    } else {
        int i = t - 512 * 64;
        if (i < 64 * 32 * 3) {
            int o = i / 96;
            int r = i - o * 96;
            int c = r / 3;
            int k = r - c * 3;
            w2t[(k * 32 + c) * 64 + o] = w2[i];
        }
    }
}

// conv1 over neighbor axis: one 32-lane segment per vertex
__global__ __launch_bounds__(256) void kA(const float* __restrict__ vp,
                                          const int* __restrict__ nb1,
                                          const float* __restrict__ wv1,
                                          const float* __restrict__ bv1,
                                          float* __restrict__ h, int V) {
    int t = blockIdx.x * 256 + threadIdx.x;
    int v = t >> 5;
    int j = t & 31;
    if (v >= V) return;
    float g = vp[nb1[v * 32 + j]];
    float gm = __shfl_up(g, 1, 32);
    if (j == 0) gm = 0.0f;
    float gp = __shfl_down(g, 1, 32);
    if (j == 31) gp = 0.0f;
    float c = wv1[0] * gm + wv1[1] * g + wv1[2] * gp + bv1[0];
    c = fmaxf(c, 0.0f);
    #pragma unroll
    for (int off = 16; off; off >>= 1) c += __shfl_xor(c, off, 32);
    if (j == 0) h[v] = c * (1.0f / 32.0f);
}

// vertex-shift 3-tap mix into 32 channels
__global__ __launch_bounds__(256) void kB(const float* __restrict__ h,
                                          const float* __restrict__ w1,
                                          const float* __restrict__ b1,
                                          float* __restrict__ f1, int V) {
    int t = blockIdx.x * 256 + threadIdx.x;
    int v = t >> 5;
    int o = t & 31;
    if (v >= V) return;
    float hm = (v > 0) ? h[v - 1] : 0.0f;
    float h0 = h[v];
    float hp = (v + 1 < V) ? h[v + 1] : 0.0f;
    f1[v * 32 + o] = fmaf(hm, w1[o * 3 + 0],
                     fmaf(h0, w1[o * 3 + 1],
                     fmaf(hp, w1[o * 3 + 2], b1[o])));
}

// conv2: 2 vertices per wave (one per 32-lane half), lane = channel.
// Each lane loads x[j] for ALL 32 j of its vertex: per load instr each
// half-wave reads one full 128B f1 row -> coalesced, 32 independent
// loads in flight per lane. Conv fully lane-local; no LDS, no barriers,
// no shuffles. V%8==0 -> no tail.
__global__ __launch_bounds__(256) void kC(const float* __restrict__ f1,
                                          const int* __restrict__ nb2,
                                          const float* __restrict__ wv2,
                                          const float* __restrict__ bv2,
                                          float* __restrict__ h2, int V) {
    int t = threadIdx.x;
    int v = blockIdx.x * 8 + (t >> 5);   // one vertex per 32-lane half-wave
    int c = t & 31;                      // channel
    if (v >= V) return;
    const int* nb = nb2 + (size_t)v * 32;

    float x[32];
    #pragma unroll
    for (int j = 0; j < 32; ++j)
        x[j] = f1[(size_t)nb[j] * 32 + c];

    float w0 = wv2[0], w1_ = wv2[1], w2_ = wv2[2], b = bv2[0];
    float s = 0.0f;
    #pragma unroll
    for (int j = 0; j < 32; ++j) {
        float pv = (j > 0)  ? x[j - 1] : 0.0f;
        float nx = (j < 31) ? x[j + 1] : 0.0f;
        float cv = fmaf(w0, pv, fmaf(w1_, x[j], fmaf(w2_, nx, b)));
        s += fmaxf(cv, 0.0f);
    }
    h2[(size_t)v * 32 + c] = s * (1.0f / 32.0f);
}

// f2 einsum: 256 threads / 32 vertices per block. h2 halo tile [34][32]
// staged in LDS via float4 vector loads; inner loop reads h2 as conflict-
// free LDS broadcasts, w2t lane-coalesced from L1.
__global__ __launch_bounds__(256) void kD(const float* __restrict__ h2,
                                          const float* __restrict__ w2t,
                                          const float* __restrict__ b2,
                                          float* __restrict__ f2, int V) {
    __shared__ float tile[34 * 32];     // 4.25 KB, rows v0-1 .. v0+32
    int t = threadIdx.x;
    int v0 = blockIdx.x * 32;

    // stage h2 halo: 34 rows x 32 ch = 272 float4
    for (int i = t; i < 272; i += 256) {
        int r = i >> 3;                 // tile row (8 float4 per row)
        int s = i & 7;
        int v = v0 - 1 + r;
        float4 val = make_float4(0.f, 0.f, 0.f, 0.f);
        if (v >= 0 && v < V)
            val = *(const float4*)(h2 + (size_t)v * 32 + s * 4);
        *(float4*)(tile + r * 32 + s * 4) = val;
    }
    __syncthreads();

    int o = t & 63;                     // output channel = lane
    int w = t >> 6;                     // wave id 0..3
    int vb = w * 8;                     // this wave's first vertex (rel. v0)
    float bo = b2[o];
    float acc[8];
    #pragma unroll
    for (int m = 0; m < 8; ++m) acc[m] = bo;

    #pragma unroll
    for (int c4 = 0; c4 < 8; ++c4) {
        float4 hv[10];
        #pragma unroll
        for (int r = 0; r < 10; ++r)
            hv[r] = *(const float4*)(tile + (vb + r) * 32 + c4 * 4);
        #pragma unroll
        for (int k = 0; k < 3; ++k) {
            #pragma unroll
            for (int cc = 0; cc < 4; ++cc) {
                int c = c4 * 4 + cc;
                float wv = w2t[(k * 32 + c) * 64 + o];
                #pragma unroll
                for (int m = 0; m < 8; ++m) {
                    float hval = (cc == 0) ? hv[m + k].x :
                                 (cc == 1) ? hv[m + k].y :
                                 (cc == 2) ? hv[m + k].z : hv[m + k].w;
                    acc[m] = fmaf(hval, wv, acc[m]);
                }
            }
        }
    }
    #pragma unroll
    for (int m = 0; m < 8; ++m) {
        int v = v0 + vb + m;
        if (v < V) f2[(size_t)v * 64 + o] = acc[m];
    }
}

#define REP16(X) X(0) X(1) X(2) X(3) X(4) X(5) X(6) X(7) \
                 X(8) X(9) X(10) X(11) X(12) X(13) X(14) X(15)

// fc + softmax: 256 threads, 16 vertices/block, thread owns TWO consecutive
// outputs (float2 accs). f2 via uniform SGPR base + immediate offsets.
// (256,6): cap ~85 VGPR -> 24 waves/CU. k-step of 8: batch 8 w-loads and
// 2x16B f s_loads per m per iter -> longer independent scheduling window.
__global__ __launch_bounds__(256, 6) void kE(const float* __restrict__ f2,
                                             const float* __restrict__ wfcT,
                                             const float* __restrict__ bfc,
                                             float* __restrict__ out, int V) {
    __shared__ float redmax[4][16];
    __shared__ float redsum[4][16];
    int t = threadIdx.x;
    int wid = t >> 6, lane = t & 63;
    int vbase = blockIdx.x * 16;
    int nv = V - vbase; if (nv > 16) nv = 16;

    const float* fb = f2 + (size_t)vbase * 64;   // uniform base -> SGPRs

    int s0 = t * 2;                          // this thread's 2 output columns
    float2 bv = *(const float2*)(bfc + s0);

#define KE_DECL(m) float2 A##m = bv;
    REP16(KE_DECL)
#undef KE_DECL

    for (int k = 0; k < 64; k += 8) {
        float2 wv[8];
        #pragma unroll
        for (int kk = 0; kk < 8; ++kk)
            wv[kk] = *(const float2*)(wfcT + (k + kk) * 512 + s0);
#define KE_FMA(m) { \
        float4 fa = *(const float4*)(fb + m * 64 + k); \
        float4 fc = *(const float4*)(fb + m * 64 + k + 4); \
        A##m.x = fmaf(fa.x, wv[0].x, fmaf(fa.y, wv[1].x, fmaf(fa.z, wv[2].x, fmaf(fa.w, wv[3].x, A##m.x)))); \
        A##m.x = fmaf(fc.x, wv[4].x, fmaf(fc.y, wv[5].x, fmaf(fc.z, wv[6].x, fmaf(fc.w, wv[7].x, A##m.x)))); \
        A##m.y = fmaf(fa.x, wv[0].y, fmaf(fa.y, wv[1].y, fmaf(fa.z, wv[2].y, fmaf(fa.w, wv[3].y, A##m.y)))); \
        A##m.y = fmaf(fc.x, wv[4].y, fmaf(fc.y, wv[5].y, fmaf(fc.z, wv[6].y, fmaf(fc.w, wv[7].y, A##m.y)))); }
        REP16(KE_FMA)
#undef KE_FMA
    }

    // softmax over 512 per vertex: wave-reduce then 4-wave combine via LDS
#define KE_MAX(m) { \
        float lm = fmaxf(A##m.x, A##m.y); \
        lm = fmaxf(lm, __shfl_xor(lm, 32)); \
        lm = fmaxf(lm, __shfl_xor(lm, 16)); \
        lm = fmaxf(lm, __shfl_xor(lm, 8)); \
        lm = fmaxf(lm, __shfl_xor(lm, 4)); \
        lm = fmaxf(lm, __shfl_xor(lm, 2)); \
        lm = fmaxf(lm, __shfl_xor(lm, 1)); \
        if (lane == 0) redmax[wid][m] = lm; }
    REP16(KE_MAX)
#undef KE_MAX
    __syncthreads();

#define KE_EXP(m) { \
        float gm = fmaxf(fmaxf(redmax[0][m], redmax[1][m]), \
                         fmaxf(redmax[2][m], redmax[3][m])); \
        A##m.x = __expf(A##m.x - gm); \
        A##m.y = __expf(A##m.y - gm); \
        float ls = A##m.x + A##m.y; \
        ls += __shfl_xor(ls, 32); \
        ls += __shfl_xor(ls, 16); \
        ls += __shfl_xor(ls, 8); \
        ls += __shfl_xor(ls, 4); \
        ls += __shfl_xor(ls, 2); \
        ls += __shfl_xor(ls, 1); \
        if (lane == 0) redsum[wid][m] = ls; }
    REP16(KE_EXP)
#undef KE_EXP
    __syncthreads();

#define KE_STORE(m) if (m < nv) { \
        float inv = 1.0f / ((redsum[0][m] + redsum[1][m]) + \
                            (redsum[2][m] + redsum[3][m])); \
        f32x2 r; r.x = A##m.x * inv; r.y = A##m.y * inv; \
        __builtin_nontemporal_store(r, \
            (f32x2*)(out + (size_t)(vbase + m) * 512 + s0)); }
    REP16(KE_STORE)
#undef KE_STORE
}

extern "C" void kernel_launch(void* const* d_in, const int* in_sizes, int n_in,
                              void* d_out, int out_size, void* d_ws, size_t ws_size,
                              hipStream_t stream) {
    (void)n_in; (void)out_size; (void)ws_size;
    const float* vp  = (const float*)d_in[0];
    const int*   nb1 = (const int*)d_in[1];
    const int*   nb2 = (const int*)d_in[2];
    const float* wv1 = (const float*)d_in[3];
    const float* bv1 = (const float*)d_in[4];
    const float* w1  = (const float*)d_in[5];
    const float* b1  = (const float*)d_in[6];
    const float* wv2 = (const float*)d_in[7];
    const float* bv2 = (const float*)d_in[8];
    const float* w2  = (const float*)d_in[9];
    const float* b2  = (const float*)d_in[10];
    const float* wfc = (const float*)d_in[11];
    const float* bfc = (const float*)d_in[12];
    float* out = (float*)d_out;
    const int V = in_sizes[0];

    float* ws = (float*)d_ws;
    size_t off = 0;
    float* h    = ws + off; off += (size_t)V;
    float* f1   = ws + off; off += (size_t)V * 32;
    float* h2   = ws + off; off += (size_t)V * 32;
    float* f2   = ws + off; off += (size_t)V * 64;
    float* wfcT = ws + off; off += 512 * 64;
    float* w2t  = ws + off; off += 3 * 32 * 64;

    k_prep<<<(512 * 64 + 64 * 32 * 3 + 255) / 256, 256, 0, stream>>>(wfc, w2, wfcT, w2t);
    kA<<<(V * 32 + 255) / 256, 256, 0, stream>>>(vp, nb1, wv1, bv1, h, V);
    kB<<<(V * 32 + 255) / 256, 256, 0, stream>>>(h, w1, b1, f1, V);
    kC<<<(V + 7) / 8, 256, 0, stream>>>(f1, nb2, wv2, bv2, h2, V);
    kD<<<(V + 31) / 32, 256, 0, stream>>>(h2, w2t, b2, f2, V);
    kE<<<(V + 15) / 16, 256, 0, stream>>>(f2, wfcT, bfc, out, V);
}

// Round 8
// 416.344 us; speedup vs baseline: 1.3264x; 1.0742x over previous
//
#include <hip/hip_runtime.h>

// ---------------------------------------------------------------------------
// Pipeline:
//  k_prep : w2[64,32,3] -> w2t[3,32,64]; wfc[512,64] -> wB{h,m,l} bf16
//           3-way-split B-fragments in MFMA order [n][s][lane][j]
//  kA     : h[v] = mean_j relu(conv3_j(vp[nb1[v,:]]))               [V]
//  kB     : f1[v,o] = h[v-1]*w1[o,0]+h[v]*w1[o,1]+h[v+1]*w1[o,2]+b1 [V,32]
//  kC     : h2[v,c] = mean_j relu(conv3_j(f1[nb2[v,j],c]))          [V,32]
//  kD     : f2[v,o] = sum_{k,c} h2[v-1+k,c]*w2t[k,c,o] + b2[o]      [V,64]
//  kE     : out[v,:] = softmax(f2[v,:] @ wfc^T + bfc)               [V,512]
//
// R11: kE moved to the MATRIX pipe. Three VALU-tuning rounds plateaued at
// 143->130->126us vs a 42us vector-FMA floor (occupancy pinned 66%, busy
// 70%). fc is a [V,64]x[64,512] GEMM; CDNA4 has no fp32 MFMA, so use a
// 3-way bf16 split (hi+mid+lo, 8 mantissa bits each ~ fp32) with the 6
// significant cross-products -> 12 mfma_f32_16x16x32_bf16 per N-tile per
// block of 16 vertices. Weights split once in k_prep into B-frag order
// (coalesced 16B/lane); f2 split per block into A-frags. MFMA total ~19us
// chip-wide; kE floor becomes the 200MB output stream (~33us).
// Layouts (guide-verified m89): A row=lane&15,k=(lane>>4)*8+j; B col=
// lane&15 same k; C/D col=lane&15,row=(lane>>4)*4+reg.
// ---------------------------------------------------------------------------

typedef short bf16x8 __attribute__((ext_vector_type(8)));
typedef float f32x4 __attribute__((ext_vector_type(4)));

__device__ inline unsigned short f2bf(float x) {
    unsigned u = __float_as_uint(x);
    unsigned r = (u + 0x7FFFu + ((u >> 16) & 1u)) >> 16;
    return (unsigned short)r;
}
__device__ inline float bf2f(unsigned short b) {
    return __uint_as_float(((unsigned)b) << 16);
}

// k_prep: w2 transpose + wfc -> 3-way bf16 split in B-fragment order.
// wB*[((n*2+s)*64+l)*8+j] = split(wfc[(n*16+(l&15))*64 + s*32+(l>>4)*8+j])
__global__ __launch_bounds__(256) void k_prep(const float* __restrict__ wfc,
                                              const float* __restrict__ w2,
                                              short* __restrict__ wBh,
                                              short* __restrict__ wBm,
                                              short* __restrict__ wBl,
                                              float* __restrict__ w2t) {
    int t = blockIdx.x * 256 + threadIdx.x;
    if (t < 32768) {
        int j = t & 7;
        int l = (t >> 3) & 63;
        int s = (t >> 9) & 1;
        int n = t >> 10;
        int col = n * 16 + (l & 15);
        int k = s * 32 + (l >> 4) * 8 + j;
        float v = wfc[col * 64 + k];
        unsigned short h = f2bf(v);
        float r1 = v - bf2f(h);
        unsigned short m = f2bf(r1);
        float r2 = r1 - bf2f(m);
        wBh[t] = (short)h;
        wBm[t] = (short)m;
        wBl[t] = (short)f2bf(r2);
    } else if (t < 32768 + 6144) {
        int i = t - 32768;
        int o = i / 96;
        int r = i - o * 96;
        int c = r / 3;
        int k = r - c * 3;
        w2t[(k * 32 + c) * 64 + o] = w2[i];
    }
}

// conv1 over neighbor axis: one 32-lane segment per vertex
__global__ __launch_bounds__(256) void kA(const float* __restrict__ vp,
                                          const int* __restrict__ nb1,
                                          const float* __restrict__ wv1,
                                          const float* __restrict__ bv1,
                                          float* __restrict__ h, int V) {
    int t = blockIdx.x * 256 + threadIdx.x;
    int v = t >> 5;
    int j = t & 31;
    if (v >= V) return;
    float g = vp[nb1[v * 32 + j]];
    float gm = __shfl_up(g, 1, 32);
    if (j == 0) gm = 0.0f;
    float gp = __shfl_down(g, 1, 32);
    if (j == 31) gp = 0.0f;
    float c = wv1[0] * gm + wv1[1] * g + wv1[2] * gp + bv1[0];
    c = fmaxf(c, 0.0f);
    #pragma unroll
    for (int off = 16; off; off >>= 1) c += __shfl_xor(c, off, 32);
    if (j == 0) h[v] = c * (1.0f / 32.0f);
}

// vertex-shift 3-tap mix into 32 channels
__global__ __launch_bounds__(256) void kB(const float* __restrict__ h,
                                          const float* __restrict__ w1,
                                          const float* __restrict__ b1,
                                          float* __restrict__ f1, int V) {
    int t = blockIdx.x * 256 + threadIdx.x;
    int v = t >> 5;
    int o = t & 31;
    if (v >= V) return;
    float hm = (v > 0) ? h[v - 1] : 0.0f;
    float h0 = h[v];
    float hp = (v + 1 < V) ? h[v + 1] : 0.0f;
    f1[v * 32 + o] = fmaf(hm, w1[o * 3 + 0],
                     fmaf(h0, w1[o * 3 + 1],
                     fmaf(hp, w1[o * 3 + 2], b1[o])));
}

// conv2: 2 vertices per wave (one per 32-lane half), lane = channel.
__global__ __launch_bounds__(256) void kC(const float* __restrict__ f1,
                                          const int* __restrict__ nb2,
                                          const float* __restrict__ wv2,
                                          const float* __restrict__ bv2,
                                          float* __restrict__ h2, int V) {
    int t = threadIdx.x;
    int v = blockIdx.x * 8 + (t >> 5);   // one vertex per 32-lane half-wave
    int c = t & 31;                      // channel
    if (v >= V) return;
    const int* nb = nb2 + (size_t)v * 32;

    float x[32];
    #pragma unroll
    for (int j = 0; j < 32; ++j)
        x[j] = f1[(size_t)nb[j] * 32 + c];

    float w0 = wv2[0], w1_ = wv2[1], w2_ = wv2[2], b = bv2[0];
    float s = 0.0f;
    #pragma unroll
    for (int j = 0; j < 32; ++j) {
        float pv = (j > 0)  ? x[j - 1] : 0.0f;
        float nx = (j < 31) ? x[j + 1] : 0.0f;
        float cv = fmaf(w0, pv, fmaf(w1_, x[j], fmaf(w2_, nx, b)));
        s += fmaxf(cv, 0.0f);
    }
    h2[(size_t)v * 32 + c] = s * (1.0f / 32.0f);
}

// f2 einsum: 256 threads / 32 vertices per block, h2 halo tile in LDS.
__global__ __launch_bounds__(256) void kD(const float* __restrict__ h2,
                                          const float* __restrict__ w2t,
                                          const float* __restrict__ b2,
                                          float* __restrict__ f2, int V) {
    __shared__ float tile[34 * 32];     // 4.25 KB, rows v0-1 .. v0+32
    int t = threadIdx.x;
    int v0 = blockIdx.x * 32;

    for (int i = t; i < 272; i += 256) {
        int r = i >> 3;
        int s = i & 7;
        int v = v0 - 1 + r;
        float4 val = make_float4(0.f, 0.f, 0.f, 0.f);
        if (v >= 0 && v < V)
            val = *(const float4*)(h2 + (size_t)v * 32 + s * 4);
        *(float4*)(tile + r * 32 + s * 4) = val;
    }
    __syncthreads();

    int o = t & 63;
    int w = t >> 6;
    int vb = w * 8;
    float bo = b2[o];
    float acc[8];
    #pragma unroll
    for (int m = 0; m < 8; ++m) acc[m] = bo;

    #pragma unroll
    for (int c4 = 0; c4 < 8; ++c4) {
        float4 hv[10];
        #pragma unroll
        for (int r = 0; r < 10; ++r)
            hv[r] = *(const float4*)(tile + (vb + r) * 32 + c4 * 4);
        #pragma unroll
        for (int k = 0; k < 3; ++k) {
            #pragma unroll
            for (int cc = 0; cc < 4; ++cc) {
                int c = c4 * 4 + cc;
                float wv = w2t[(k * 32 + c) * 64 + o];
                #pragma unroll
                for (int m = 0; m < 8; ++m) {
                    float hval = (cc == 0) ? hv[m + k].x :
                                 (cc == 1) ? hv[m + k].y :
                                 (cc == 2) ? hv[m + k].z : hv[m + k].w;
                    acc[m] = fmaf(hval, wv, acc[m]);
                }
            }
        }
    }
    #pragma unroll
    for (int m = 0; m < 8; ++m) {
        int v = v0 + vb + m;
        if (v < V) f2[(size_t)v * 64 + o] = acc[m];
    }
}

// fc + softmax on the MATRIX pipe. 256 thr / 16 vertices / block.
// Wave w owns N-tiles w*8..w*8+7 (cols w*128..+127). A = f2 rows split
// 3-way to bf16 frags; B preconverted in k_prep. 12 MFMA per tile.
// C/D: col=lane&15, row=(lane>>4)*4+reg.
__global__ __launch_bounds__(256) void kE(const float* __restrict__ f2,
                                          const short* __restrict__ wBh,
                                          const short* __restrict__ wBm,
                                          const short* __restrict__ wBl,
                                          const float* __restrict__ bfc,
                                          float* __restrict__ out, int V) {
    __shared__ float redmax[4][16];
    __shared__ float redsum[4][16];
    int t = threadIdx.x;
    int w = t >> 6;          // wave 0..3
    int l = t & 63;          // lane
    int c16 = l & 15;
    int g = l >> 4;          // K-group / row-group
    int vbase = blockIdx.x * 16;   // V % 16 == 0

    // ---- A fragments: rows = vertices, 3-way bf16 split ----
    const float* rowp = f2 + (size_t)(vbase + c16) * 64 + g * 8;
    float4 q0 = *(const float4*)(rowp);        // s=0, k=g*8..+3
    float4 q1 = *(const float4*)(rowp + 4);    // s=0, k=g*8+4..+7
    float4 q2 = *(const float4*)(rowp + 32);   // s=1
    float4 q3 = *(const float4*)(rowp + 36);

    bf16x8 ah0, am0, al0, ah1, am1, al1;
#define SPLIT(AH, AM, AL, idx, x) { \
        float xx = (x); \
        unsigned short h_ = f2bf(xx); \
        float r1_ = xx - bf2f(h_); \
        unsigned short m_ = f2bf(r1_); \
        float r2_ = r1_ - bf2f(m_); \
        AH[idx] = (short)h_; AM[idx] = (short)m_; AL[idx] = (short)f2bf(r2_); }
    SPLIT(ah0, am0, al0, 0, q0.x) SPLIT(ah0, am0, al0, 1, q0.y)
    SPLIT(ah0, am0, al0, 2, q0.z) SPLIT(ah0, am0, al0, 3, q0.w)
    SPLIT(ah0, am0, al0, 4, q1.x) SPLIT(ah0, am0, al0, 5, q1.y)
    SPLIT(ah0, am0, al0, 6, q1.z) SPLIT(ah0, am0, al0, 7, q1.w)
    SPLIT(ah1, am1, al1, 0, q2.x) SPLIT(ah1, am1, al1, 1, q2.y)
    SPLIT(ah1, am1, al1, 2, q2.z) SPLIT(ah1, am1, al1, 3, q2.w)
    SPLIT(ah1, am1, al1, 4, q3.x) SPLIT(ah1, am1, al1, 5, q3.y)
    SPLIT(ah1, am1, al1, 6, q3.z) SPLIT(ah1, am1, al1, 7, q3.w)
#undef SPLIT

    // ---- MFMA: 8 N-tiles per wave, 2 K-steps, 6 significant products ----
    f32x4 acc[8];
    const bf16x8* Bh = (const bf16x8*)wBh;
    const bf16x8* Bm = (const bf16x8*)wBm;
    const bf16x8* Bl = (const bf16x8*)wBl;
    #pragma unroll
    for (int n8 = 0; n8 < 8; ++n8) {
        int n = w * 8 + n8;
        bf16x8 bh0 = Bh[(n * 2 + 0) * 64 + l];
        bf16x8 bm0 = Bm[(n * 2 + 0) * 64 + l];
        bf16x8 bl0 = Bl[(n * 2 + 0) * 64 + l];
        bf16x8 bh1 = Bh[(n * 2 + 1) * 64 + l];
        bf16x8 bm1 = Bm[(n * 2 + 1) * 64 + l];
        bf16x8 bl1 = Bl[(n * 2 + 1) * 64 + l];
        f32x4 c = {0.f, 0.f, 0.f, 0.f};
        c = __builtin_amdgcn_mfma_f32_16x16x32_bf16(ah0, bh0, c, 0, 0, 0);
        c = __builtin_amdgcn_mfma_f32_16x16x32_bf16(ah0, bm0, c, 0, 0, 0);
        c = __builtin_amdgcn_mfma_f32_16x16x32_bf16(am0, bh0, c, 0, 0, 0);
        c = __builtin_amdgcn_mfma_f32_16x16x32_bf16(ah0, bl0, c, 0, 0, 0);
        c = __builtin_amdgcn_mfma_f32_16x16x32_bf16(am0, bm0, c, 0, 0, 0);
        c = __builtin_amdgcn_mfma_f32_16x16x32_bf16(al0, bh0, c, 0, 0, 0);
        c = __builtin_amdgcn_mfma_f32_16x16x32_bf16(ah1, bh1, c, 0, 0, 0);
        c = __builtin_amdgcn_mfma_f32_16x16x32_bf16(ah1, bm1, c, 0, 0, 0);
        c = __builtin_amdgcn_mfma_f32_16x16x32_bf16(am1, bh1, c, 0, 0, 0);
        c = __builtin_amdgcn_mfma_f32_16x16x32_bf16(ah1, bl1, c, 0, 0, 0);
        c = __builtin_amdgcn_mfma_f32_16x16x32_bf16(am1, bm1, c, 0, 0, 0);
        c = __builtin_amdgcn_mfma_f32_16x16x32_bf16(al1, bh1, c, 0, 0, 0);
        float bn = bfc[n * 16 + c16];
        c.x += bn; c.y += bn; c.z += bn; c.w += bn;
        acc[n8] = c;
    }

    // ---- softmax: per reg j, row r = g*4+j; reduce 16 lanes then 4 waves --
    float lmax0 = -1e30f, lmax1 = -1e30f, lmax2 = -1e30f, lmax3 = -1e30f;
    #pragma unroll
    for (int n8 = 0; n8 < 8; ++n8) {
        lmax0 = fmaxf(lmax0, acc[n8].x);
        lmax1 = fmaxf(lmax1, acc[n8].y);
        lmax2 = fmaxf(lmax2, acc[n8].z);
        lmax3 = fmaxf(lmax3, acc[n8].w);
    }
    #pragma unroll
    for (int off = 8; off; off >>= 1) {
        lmax0 = fmaxf(lmax0, __shfl_xor(lmax0, off));
        lmax1 = fmaxf(lmax1, __shfl_xor(lmax1, off));
        lmax2 = fmaxf(lmax2, __shfl_xor(lmax2, off));
        lmax3 = fmaxf(lmax3, __shfl_xor(lmax3, off));
    }
    if (c16 == 0) {
        redmax[w][g * 4 + 0] = lmax0;
        redmax[w][g * 4 + 1] = lmax1;
        redmax[w][g * 4 + 2] = lmax2;
        redmax[w][g * 4 + 3] = lmax3;
    }
    __syncthreads();
    float gm0 = fmaxf(fmaxf(redmax[0][g * 4 + 0], redmax[1][g * 4 + 0]),
                      fmaxf(redmax[2][g * 4 + 0], redmax[3][g * 4 + 0]));
    float gm1 = fmaxf(fmaxf(redmax[0][g * 4 + 1], redmax[1][g * 4 + 1]),
                      fmaxf(redmax[2][g * 4 + 1], redmax[3][g * 4 + 1]));
    float gm2 = fmaxf(fmaxf(redmax[0][g * 4 + 2], redmax[1][g * 4 + 2]),
                      fmaxf(redmax[2][g * 4 + 2], redmax[3][g * 4 + 2]));
    float gm3 = fmaxf(fmaxf(redmax[0][g * 4 + 3], redmax[1][g * 4 + 3]),
                      fmaxf(redmax[2][g * 4 + 3], redmax[3][g * 4 + 3]));

    float ls0 = 0.f, ls1 = 0.f, ls2 = 0.f, ls3 = 0.f;
    #pragma unroll
    for (int n8 = 0; n8 < 8; ++n8) {
        acc[n8].x = __expf(acc[n8].x - gm0); ls0 += acc[n8].x;
        acc[n8].y = __expf(acc[n8].y - gm1); ls1 += acc[n8].y;
        acc[n8].z = __expf(acc[n8].z - gm2); ls2 += acc[n8].z;
        acc[n8].w = __expf(acc[n8].w - gm3); ls3 += acc[n8].w;
    }
    #pragma unroll
    for (int off = 8; off; off >>= 1) {
        ls0 += __shfl_xor(ls0, off);
        ls1 += __shfl_xor(ls1, off);
        ls2 += __shfl_xor(ls2, off);
        ls3 += __shfl_xor(ls3, off);
    }
    if (c16 == 0) {
        redsum[w][g * 4 + 0] = ls0;
        redsum[w][g * 4 + 1] = ls1;
        redsum[w][g * 4 + 2] = ls2;
        redsum[w][g * 4 + 3] = ls3;
    }
    __syncthreads();
    float inv0 = 1.0f / (redsum[0][g * 4 + 0] + redsum[1][g * 4 + 0] +
                         redsum[2][g * 4 + 0] + redsum[3][g * 4 + 0]);
    float inv1 = 1.0f / (redsum[0][g * 4 + 1] + redsum[1][g * 4 + 1] +
                         redsum[2][g * 4 + 1] + redsum[3][g * 4 + 1]);
    float inv2 = 1.0f / (redsum[0][g * 4 + 2] + redsum[1][g * 4 + 2] +
                         redsum[2][g * 4 + 2] + redsum[3][g * 4 + 2]);
    float inv3 = 1.0f / (redsum[0][g * 4 + 3] + redsum[1][g * 4 + 3] +
                         redsum[2][g * 4 + 3] + redsum[3][g * 4 + 3]);

    // ---- store: out[(vbase+g*4+j)*512 + n*16 + c16] ----
    #pragma unroll
    for (int n8 = 0; n8 < 8; ++n8) {
        int n = w * 8 + n8;
        float* op = out + (size_t)(vbase + g * 4) * 512 + n * 16 + c16;
        __builtin_nontemporal_store(acc[n8].x * inv0, op);
        __builtin_nontemporal_store(acc[n8].y * inv1, op + 512);
        __builtin_nontemporal_store(acc[n8].z * inv2, op + 1024);
        __builtin_nontemporal_store(acc[n8].w * inv3, op + 1536);
    }
}

extern "C" void kernel_launch(void* const* d_in, const int* in_sizes, int n_in,
                              void* d_out, int out_size, void* d_ws, size_t ws_size,
                              hipStream_t stream) {
    (void)n_in; (void)out_size; (void)ws_size;
    const float* vp  = (const float*)d_in[0];
    const int*   nb1 = (const int*)d_in[1];
    const int*   nb2 = (const int*)d_in[2];
    const float* wv1 = (const float*)d_in[3];
    const float* bv1 = (const float*)d_in[4];
    const float* w1  = (const float*)d_in[5];
    const float* b1  = (const float*)d_in[6];
    const float* wv2 = (const float*)d_in[7];
    const float* bv2 = (const float*)d_in[8];
    const float* w2  = (const float*)d_in[9];
    const float* b2  = (const float*)d_in[10];
    const float* wfc = (const float*)d_in[11];
    const float* bfc = (const float*)d_in[12];
    float* out = (float*)d_out;
    const int V = in_sizes[0];

    float* ws = (float*)d_ws;
    size_t off = 0;
    float* h    = ws + off; off += (size_t)V;
    float* f1   = ws + off; off += (size_t)V * 32;
    float* h2   = ws + off; off += (size_t)V * 32;
    float* f2   = ws + off; off += (size_t)V * 64;
    float* w2t  = ws + off; off += 3 * 32 * 64;
    short* wBh  = (short*)(ws + off); off += 32768 / 2;   // 32768 shorts
    short* wBm  = (short*)(ws + off); off += 32768 / 2;
    short* wBl  = (short*)(ws + off); off += 32768 / 2;

    k_prep<<<(32768 + 6144 + 255) / 256, 256, 0, stream>>>(wfc, w2, wBh, wBm, wBl, w2t);
    kA<<<(V * 32 + 255) / 256, 256, 0, stream>>>(vp, nb1, wv1, bv1, h, V);
    kB<<<(V * 32 + 255) / 256, 256, 0, stream>>>(h, w1, b1, f1, V);
    kC<<<(V + 7) / 8, 256, 0, stream>>>(f1, nb2, wv2, bv2, h2, V);
    kD<<<(V + 31) / 32, 256, 0, stream>>>(h2, w2t, b2, f2, V);
    kE<<<V / 16, 256, 0, stream>>>(f2, wBh, wBm, wBl, bfc, out, V);
}

// Round 9
// 415.290 us; speedup vs baseline: 1.3297x; 1.0025x over previous
//
#include <hip/hip_runtime.h>

// ---------------------------------------------------------------------------
// Pipeline:
//  k_prep : w2[64,32,3] -> w2t[3,32,64]; wfc[512,64] -> wB{h,m,l} bf16
//           3-way-split B-fragments in MFMA order [n][s][lane][j]
//  kA     : h[v] = mean_j relu(conv3_j(vp[nb1[v,:]]))               [V]
//  kB     : f1[v,o] = h[v-1]*w1[o,0]+h[v]*w1[o,1]+h[v+1]*w1[o,2]+b1 [V,32]
//  kC     : h2[v,c] = mean_j relu(conv3_j(f1[nb2[v,j],c]))          [V,32]
//  kD     : f2[v,o] = sum_{k,c} h2[v-1+k,c]*w2t[k,c,o] + b2[o]      [V,64]
//  kE     : out[v,:] = softmax(f2[v,:] @ wfc^T + bfc)               [V,512]
//
// R12 changes:
//  kE: 32 rows/block (was 16). Each block read the FULL 192KB split-B ->
//      6250 blocks x 192KB = 1.2GB L2/L3 traffic (~35us), rivaling the
//      19us of MFMA. Two A-row-sets per wave: B frag loaded once feeds
//      24 MFMAs (was 12); B traffic halves to 600MB. V%32==0.
//  kC: nb[j] was half-wave-uniform -> compiler emitted 32 per-lane
//      broadcast loads on top of the 32 f1 gathers (64 VMEM/lane).
//      Now ONE nb load per lane (lane c holds nb[c]) + __shfl(nbl,j,32):
//      32 VALU shuffles replace 32 VMEM broadcasts. (256,8) pins 8
//      waves/SIMD (~45 live VGPR).
// ---------------------------------------------------------------------------

typedef short bf16x8 __attribute__((ext_vector_type(8)));
typedef float f32x4 __attribute__((ext_vector_type(4)));

__device__ inline unsigned short f2bf(float x) {
    unsigned u = __float_as_uint(x);
    unsigned r = (u + 0x7FFFu + ((u >> 16) & 1u)) >> 16;
    return (unsigned short)r;
}
__device__ inline float bf2f(unsigned short b) {
    return __uint_as_float(((unsigned)b) << 16);
}

// k_prep: w2 transpose + wfc -> 3-way bf16 split in B-fragment order.
// wB*[((n*2+s)*64+l)*8+j] = split(wfc[(n*16+(l&15))*64 + s*32+(l>>4)*8+j])
__global__ __launch_bounds__(256) void k_prep(const float* __restrict__ wfc,
                                              const float* __restrict__ w2,
                                              short* __restrict__ wBh,
                                              short* __restrict__ wBm,
                                              short* __restrict__ wBl,
                                              float* __restrict__ w2t) {
    int t = blockIdx.x * 256 + threadIdx.x;
    if (t < 32768) {
        int j = t & 7;
        int l = (t >> 3) & 63;
        int s = (t >> 9) & 1;
        int n = t >> 10;
        int col = n * 16 + (l & 15);
        int k = s * 32 + (l >> 4) * 8 + j;
        float v = wfc[col * 64 + k];
        unsigned short h = f2bf(v);
        float r1 = v - bf2f(h);
        unsigned short m = f2bf(r1);
        float r2 = r1 - bf2f(m);
        wBh[t] = (short)h;
        wBm[t] = (short)m;
        wBl[t] = (short)f2bf(r2);
    } else if (t < 32768 + 6144) {
        int i = t - 32768;
        int o = i / 96;
        int r = i - o * 96;
        int c = r / 3;
        int k = r - c * 3;
        w2t[(k * 32 + c) * 64 + o] = w2[i];
    }
}

// conv1 over neighbor axis: one 32-lane segment per vertex
__global__ __launch_bounds__(256) void kA(const float* __restrict__ vp,
                                          const int* __restrict__ nb1,
                                          const float* __restrict__ wv1,
                                          const float* __restrict__ bv1,
                                          float* __restrict__ h, int V) {
    int t = blockIdx.x * 256 + threadIdx.x;
    int v = t >> 5;
    int j = t & 31;
    if (v >= V) return;
    float g = vp[nb1[v * 32 + j]];
    float gm = __shfl_up(g, 1, 32);
    if (j == 0) gm = 0.0f;
    float gp = __shfl_down(g, 1, 32);
    if (j == 31) gp = 0.0f;
    float c = wv1[0] * gm + wv1[1] * g + wv1[2] * gp + bv1[0];
    c = fmaxf(c, 0.0f);
    #pragma unroll
    for (int off = 16; off; off >>= 1) c += __shfl_xor(c, off, 32);
    if (j == 0) h[v] = c * (1.0f / 32.0f);
}

// vertex-shift 3-tap mix into 32 channels
__global__ __launch_bounds__(256) void kB(const float* __restrict__ h,
                                          const float* __restrict__ w1,
                                          const float* __restrict__ b1,
                                          float* __restrict__ f1, int V) {
    int t = blockIdx.x * 256 + threadIdx.x;
    int v = t >> 5;
    int o = t & 31;
    if (v >= V) return;
    float hm = (v > 0) ? h[v - 1] : 0.0f;
    float h0 = h[v];
    float hp = (v + 1 < V) ? h[v + 1] : 0.0f;
    f1[v * 32 + o] = fmaf(hm, w1[o * 3 + 0],
                     fmaf(h0, w1[o * 3 + 1],
                     fmaf(hp, w1[o * 3 + 2], b1[o])));
}

// conv2: 2 vertices per wave (one per 32-lane half), lane = channel.
// ONE nb load per lane (lane c holds nb[c]); j-walk gets indices via
// __shfl within the half-wave -> 32 VMEM broadcasts become 32 VALU ops.
__global__ __launch_bounds__(256, 8) void kC(const float* __restrict__ f1,
                                             const int* __restrict__ nb2,
                                             const float* __restrict__ wv2,
                                             const float* __restrict__ bv2,
                                             float* __restrict__ h2, int V) {
    int t = threadIdx.x;
    int v = blockIdx.x * 8 + (t >> 5);   // one vertex per 32-lane half-wave
    int c = t & 31;                      // channel
    if (v >= V) return;
    int nbl = nb2[(size_t)v * 32 + c];   // lane c holds nb[c]

    float x[32];
    #pragma unroll
    for (int j = 0; j < 32; ++j) {
        int idx = __shfl(nbl, j, 32);
        x[j] = f1[(size_t)idx * 32 + c];
    }

    float w0 = wv2[0], w1_ = wv2[1], w2_ = wv2[2], b = bv2[0];
    float s = 0.0f;
    #pragma unroll
    for (int j = 0; j < 32; ++j) {
        float pv = (j > 0)  ? x[j - 1] : 0.0f;
        float nx = (j < 31) ? x[j + 1] : 0.0f;
        float cv = fmaf(w0, pv, fmaf(w1_, x[j], fmaf(w2_, nx, b)));
        s += fmaxf(cv, 0.0f);
    }
    h2[(size_t)v * 32 + c] = s * (1.0f / 32.0f);
}

// f2 einsum: 256 threads / 32 vertices per block, h2 halo tile in LDS.
__global__ __launch_bounds__(256) void kD(const float* __restrict__ h2,
                                          const float* __restrict__ w2t,
                                          const float* __restrict__ b2,
                                          float* __restrict__ f2, int V) {
    __shared__ float tile[34 * 32];     // 4.25 KB, rows v0-1 .. v0+32
    int t = threadIdx.x;
    int v0 = blockIdx.x * 32;

    for (int i = t; i < 272; i += 256) {
        int r = i >> 3;
        int s = i & 7;
        int v = v0 - 1 + r;
        float4 val = make_float4(0.f, 0.f, 0.f, 0.f);
        if (v >= 0 && v < V)
            val = *(const float4*)(h2 + (size_t)v * 32 + s * 4);
        *(float4*)(tile + r * 32 + s * 4) = val;
    }
    __syncthreads();

    int o = t & 63;
    int w = t >> 6;
    int vb = w * 8;
    float bo = b2[o];
    float acc[8];
    #pragma unroll
    for (int m = 0; m < 8; ++m) acc[m] = bo;

    #pragma unroll
    for (int c4 = 0; c4 < 8; ++c4) {
        float4 hv[10];
        #pragma unroll
        for (int r = 0; r < 10; ++r)
            hv[r] = *(const float4*)(tile + (vb + r) * 32 + c4 * 4);
        #pragma unroll
        for (int k = 0; k < 3; ++k) {
            #pragma unroll
            for (int cc = 0; cc < 4; ++cc) {
                int c = c4 * 4 + cc;
                float wv = w2t[(k * 32 + c) * 64 + o];
                #pragma unroll
                for (int m = 0; m < 8; ++m) {
                    float hval = (cc == 0) ? hv[m + k].x :
                                 (cc == 1) ? hv[m + k].y :
                                 (cc == 2) ? hv[m + k].z : hv[m + k].w;
                    acc[m] = fmaf(hval, wv, acc[m]);
                }
            }
        }
    }
    #pragma unroll
    for (int m = 0; m < 8; ++m) {
        int v = v0 + vb + m;
        if (v < V) f2[(size_t)v * 64 + o] = acc[m];
    }
}

// fc + softmax on the MATRIX pipe. 256 thr / 32 vertices / block.
// Two A-row-sets per wave (rows vbase+c16, vbase+16+c16); each B frag
// load feeds 24 MFMAs. Wave w owns N-tiles w*8..w*8+7.
// C/D: col=lane&15, row=(lane>>4)*4+reg.
__global__ __launch_bounds__(256) void kE(const float* __restrict__ f2,
                                          const short* __restrict__ wBh,
                                          const short* __restrict__ wBm,
                                          const short* __restrict__ wBl,
                                          const float* __restrict__ bfc,
                                          float* __restrict__ out, int V) {
    __shared__ float redmax[4][32];
    __shared__ float redsum[4][32];
    int t = threadIdx.x;
    int w = t >> 6;          // wave 0..3
    int l = t & 63;          // lane
    int c16 = l & 15;
    int g = l >> 4;          // K-group / row-group
    int vbase = blockIdx.x * 32;   // V % 32 == 0

    // ---- A fragments: two row-sets, 3-way bf16 split ----
    bf16x8 ah0[2], am0[2], al0[2], ah1[2], am1[2], al1[2];
#define SPLIT(AH, AM, AL, idx, x) { \
        float xx = (x); \
        unsigned short h_ = f2bf(xx); \
        float r1_ = xx - bf2f(h_); \
        unsigned short m_ = f2bf(r1_); \
        float r2_ = r1_ - bf2f(m_); \
        AH[idx] = (short)h_; AM[idx] = (short)m_; AL[idx] = (short)f2bf(r2_); }
    #pragma unroll
    for (int set = 0; set < 2; ++set) {
        const float* rowp = f2 + (size_t)(vbase + set * 16 + c16) * 64 + g * 8;
        float4 q0 = *(const float4*)(rowp);        // s=0, k=g*8..+3
        float4 q1 = *(const float4*)(rowp + 4);    // s=0, k=g*8+4..+7
        float4 q2 = *(const float4*)(rowp + 32);   // s=1
        float4 q3 = *(const float4*)(rowp + 36);
        SPLIT(ah0[set], am0[set], al0[set], 0, q0.x)
        SPLIT(ah0[set], am0[set], al0[set], 1, q0.y)
        SPLIT(ah0[set], am0[set], al0[set], 2, q0.z)
        SPLIT(ah0[set], am0[set], al0[set], 3, q0.w)
        SPLIT(ah0[set], am0[set], al0[set], 4, q1.x)
        SPLIT(ah0[set], am0[set], al0[set], 5, q1.y)
        SPLIT(ah0[set], am0[set], al0[set], 6, q1.z)
        SPLIT(ah0[set], am0[set], al0[set], 7, q1.w)
        SPLIT(ah1[set], am1[set], al1[set], 0, q2.x)
        SPLIT(ah1[set], am1[set], al1[set], 1, q2.y)
        SPLIT(ah1[set], am1[set], al1[set], 2, q2.z)
        SPLIT(ah1[set], am1[set], al1[set], 3, q2.w)
        SPLIT(ah1[set], am1[set], al1[set], 4, q3.x)
        SPLIT(ah1[set], am1[set], al1[set], 5, q3.y)
        SPLIT(ah1[set], am1[set], al1[set], 6, q3.z)
        SPLIT(ah1[set], am1[set], al1[set], 7, q3.w)
    }
#undef SPLIT

    // ---- MFMA: 8 N-tiles per wave, 2 K-steps, 6 products, 2 row-sets ----
    f32x4 accA[8], accB[8];
    const bf16x8* Bh = (const bf16x8*)wBh;
    const bf16x8* Bm = (const bf16x8*)wBm;
    const bf16x8* Bl = (const bf16x8*)wBl;
    #pragma unroll
    for (int n8 = 0; n8 < 8; ++n8) {
        int n = w * 8 + n8;
        bf16x8 bh0 = Bh[(n * 2 + 0) * 64 + l];
        bf16x8 bm0 = Bm[(n * 2 + 0) * 64 + l];
        bf16x8 bl0 = Bl[(n * 2 + 0) * 64 + l];
        bf16x8 bh1 = Bh[(n * 2 + 1) * 64 + l];
        bf16x8 bm1 = Bm[(n * 2 + 1) * 64 + l];
        bf16x8 bl1 = Bl[(n * 2 + 1) * 64 + l];
        float bn = bfc[n * 16 + c16];
        f32x4 cA = {0.f, 0.f, 0.f, 0.f};
        cA = __builtin_amdgcn_mfma_f32_16x16x32_bf16(ah0[0], bh0, cA, 0, 0, 0);
        cA = __builtin_amdgcn_mfma_f32_16x16x32_bf16(ah0[0], bm0, cA, 0, 0, 0);
        cA = __builtin_amdgcn_mfma_f32_16x16x32_bf16(am0[0], bh0, cA, 0, 0, 0);
        cA = __builtin_amdgcn_mfma_f32_16x16x32_bf16(ah0[0], bl0, cA, 0, 0, 0);
        cA = __builtin_amdgcn_mfma_f32_16x16x32_bf16(am0[0], bm0, cA, 0, 0, 0);
        cA = __builtin_amdgcn_mfma_f32_16x16x32_bf16(al0[0], bh0, cA, 0, 0, 0);
        cA = __builtin_amdgcn_mfma_f32_16x16x32_bf16(ah1[0], bh1, cA, 0, 0, 0);
        cA = __builtin_amdgcn_mfma_f32_16x16x32_bf16(ah1[0], bm1, cA, 0, 0, 0);
        cA = __builtin_amdgcn_mfma_f32_16x16x32_bf16(am1[0], bh1, cA, 0, 0, 0);
        cA = __builtin_amdgcn_mfma_f32_16x16x32_bf16(ah1[0], bl1, cA, 0, 0, 0);
        cA = __builtin_amdgcn_mfma_f32_16x16x32_bf16(am1[0], bm1, cA, 0, 0, 0);
        cA = __builtin_amdgcn_mfma_f32_16x16x32_bf16(al1[0], bh1, cA, 0, 0, 0);
        cA.x += bn; cA.y += bn; cA.z += bn; cA.w += bn;
        accA[n8] = cA;
        f32x4 cB = {0.f, 0.f, 0.f, 0.f};
        cB = __builtin_amdgcn_mfma_f32_16x16x32_bf16(ah0[1], bh0, cB, 0, 0, 0);
        cB = __builtin_amdgcn_mfma_f32_16x16x32_bf16(ah0[1], bm0, cB, 0, 0, 0);
        cB = __builtin_amdgcn_mfma_f32_16x16x32_bf16(am0[1], bh0, cB, 0, 0, 0);
        cB = __builtin_amdgcn_mfma_f32_16x16x32_bf16(ah0[1], bl0, cB, 0, 0, 0);
        cB = __builtin_amdgcn_mfma_f32_16x16x32_bf16(am0[1], bm0, cB, 0, 0, 0);
        cB = __builtin_amdgcn_mfma_f32_16x16x32_bf16(al0[1], bh0, cB, 0, 0, 0);
        cB = __builtin_amdgcn_mfma_f32_16x16x32_bf16(ah1[1], bh1, cB, 0, 0, 0);
        cB = __builtin_amdgcn_mfma_f32_16x16x32_bf16(ah1[1], bm1, cB, 0, 0, 0);
        cB = __builtin_amdgcn_mfma_f32_16x16x32_bf16(am1[1], bh1, cB, 0, 0, 0);
        cB = __builtin_amdgcn_mfma_f32_16x16x32_bf16(ah1[1], bl1, cB, 0, 0, 0);
        cB = __builtin_amdgcn_mfma_f32_16x16x32_bf16(am1[1], bm1, cB, 0, 0, 0);
        cB = __builtin_amdgcn_mfma_f32_16x16x32_bf16(al1[1], bh1, cB, 0, 0, 0);
        cB.x += bn; cB.y += bn; cB.z += bn; cB.w += bn;
        accB[n8] = cB;
    }

    // ---- softmax: per reg j, set s: row = s*16 + g*4 + j ----
    float mA0 = -1e30f, mA1 = -1e30f, mA2 = -1e30f, mA3 = -1e30f;
    float mB0 = -1e30f, mB1 = -1e30f, mB2 = -1e30f, mB3 = -1e30f;
    #pragma unroll
    for (int n8 = 0; n8 < 8; ++n8) {
        mA0 = fmaxf(mA0, accA[n8].x); mA1 = fmaxf(mA1, accA[n8].y);
        mA2 = fmaxf(mA2, accA[n8].z); mA3 = fmaxf(mA3, accA[n8].w);
        mB0 = fmaxf(mB0, accB[n8].x); mB1 = fmaxf(mB1, accB[n8].y);
        mB2 = fmaxf(mB2, accB[n8].z); mB3 = fmaxf(mB3, accB[n8].w);
    }
    #pragma unroll
    for (int off = 8; off; off >>= 1) {
        mA0 = fmaxf(mA0, __shfl_xor(mA0, off));
        mA1 = fmaxf(mA1, __shfl_xor(mA1, off));
        mA2 = fmaxf(mA2, __shfl_xor(mA2, off));
        mA3 = fmaxf(mA3, __shfl_xor(mA3, off));
        mB0 = fmaxf(mB0, __shfl_xor(mB0, off));
        mB1 = fmaxf(mB1, __shfl_xor(mB1, off));
        mB2 = fmaxf(mB2, __shfl_xor(mB2, off));
        mB3 = fmaxf(mB3, __shfl_xor(mB3, off));
    }
    if (c16 == 0) {
        redmax[w][g * 4 + 0] = mA0;  redmax[w][g * 4 + 1] = mA1;
        redmax[w][g * 4 + 2] = mA2;  redmax[w][g * 4 + 3] = mA3;
        redmax[w][16 + g * 4 + 0] = mB0;  redmax[w][16 + g * 4 + 1] = mB1;
        redmax[w][16 + g * 4 + 2] = mB2;  redmax[w][16 + g * 4 + 3] = mB3;
    }
    __syncthreads();
#define GMAX(r) fmaxf(fmaxf(redmax[0][r], redmax[1][r]), \
                      fmaxf(redmax[2][r], redmax[3][r]))
    float gA0 = GMAX(g * 4 + 0), gA1 = GMAX(g * 4 + 1);
    float gA2 = GMAX(g * 4 + 2), gA3 = GMAX(g * 4 + 3);
    float gB0 = GMAX(16 + g * 4 + 0), gB1 = GMAX(16 + g * 4 + 1);
    float gB2 = GMAX(16 + g * 4 + 2), gB3 = GMAX(16 + g * 4 + 3);
#undef GMAX

    float sA0 = 0.f, sA1 = 0.f, sA2 = 0.f, sA3 = 0.f;
    float sB0 = 0.f, sB1 = 0.f, sB2 = 0.f, sB3 = 0.f;
    #pragma unroll
    for (int n8 = 0; n8 < 8; ++n8) {
        accA[n8].x = __expf(accA[n8].x - gA0); sA0 += accA[n8].x;
        accA[n8].y = __expf(accA[n8].y - gA1); sA1 += accA[n8].y;
        accA[n8].z = __expf(accA[n8].z - gA2); sA2 += accA[n8].z;
        accA[n8].w = __expf(accA[n8].w - gA3); sA3 += accA[n8].w;
        accB[n8].x = __expf(accB[n8].x - gB0); sB0 += accB[n8].x;
        accB[n8].y = __expf(accB[n8].y - gB1); sB1 += accB[n8].y;
        accB[n8].z = __expf(accB[n8].z - gB2); sB2 += accB[n8].z;
        accB[n8].w = __expf(accB[n8].w - gB3); sB3 += accB[n8].w;
    }
    #pragma unroll
    for (int off = 8; off; off >>= 1) {
        sA0 += __shfl_xor(sA0, off); sA1 += __shfl_xor(sA1, off);
        sA2 += __shfl_xor(sA2, off); sA3 += __shfl_xor(sA3, off);
        sB0 += __shfl_xor(sB0, off); sB1 += __shfl_xor(sB1, off);
        sB2 += __shfl_xor(sB2, off); sB3 += __shfl_xor(sB3, off);
    }
    if (c16 == 0) {
        redsum[w][g * 4 + 0] = sA0;  redsum[w][g * 4 + 1] = sA1;
        redsum[w][g * 4 + 2] = sA2;  redsum[w][g * 4 + 3] = sA3;
        redsum[w][16 + g * 4 + 0] = sB0;  redsum[w][16 + g * 4 + 1] = sB1;
        redsum[w][16 + g * 4 + 2] = sB2;  redsum[w][16 + g * 4 + 3] = sB3;
    }
    __syncthreads();
#define GSUM(r) (redsum[0][r] + redsum[1][r] + redsum[2][r] + redsum[3][r])
    float iA0 = 1.0f / GSUM(g * 4 + 0), iA1 = 1.0f / GSUM(g * 4 + 1);
    float iA2 = 1.0f / GSUM(g * 4 + 2), iA3 = 1.0f / GSUM(g * 4 + 3);
    float iB0 = 1.0f / GSUM(16 + g * 4 + 0), iB1 = 1.0f / GSUM(16 + g * 4 + 1);
    float iB2 = 1.0f / GSUM(16 + g * 4 + 2), iB3 = 1.0f / GSUM(16 + g * 4 + 3);
#undef GSUM

    // ---- store: out[(vbase+s*16+g*4+j)*512 + n*16 + c16] ----
    #pragma unroll
    for (int n8 = 0; n8 < 8; ++n8) {
        int n = w * 8 + n8;
        float* opA = out + (size_t)(vbase + g * 4) * 512 + n * 16 + c16;
        __builtin_nontemporal_store(accA[n8].x * iA0, opA);
        __builtin_nontemporal_store(accA[n8].y * iA1, opA + 512);
        __builtin_nontemporal_store(accA[n8].z * iA2, opA + 1024);
        __builtin_nontemporal_store(accA[n8].w * iA3, opA + 1536);
        float* opB = opA + 16 * 512;
        __builtin_nontemporal_store(accB[n8].x * iB0, opB);
        __builtin_nontemporal_store(accB[n8].y * iB1, opB + 512);
        __builtin_nontemporal_store(accB[n8].z * iB2, opB + 1024);
        __builtin_nontemporal_store(accB[n8].w * iB3, opB + 1536);
    }
}

extern "C" void kernel_launch(void* const* d_in, const int* in_sizes, int n_in,
                              void* d_out, int out_size, void* d_ws, size_t ws_size,
                              hipStream_t stream) {
    (void)n_in; (void)out_size; (void)ws_size;
    const float* vp  = (const float*)d_in[0];
    const int*   nb1 = (const int*)d_in[1];
    const int*   nb2 = (const int*)d_in[2];
    const float* wv1 = (const float*)d_in[3];
    const float* bv1 = (const float*)d_in[4];
    const float* w1  = (const float*)d_in[5];
    const float* b1  = (const float*)d_in[6];
    const float* wv2 = (const float*)d_in[7];
    const float* bv2 = (const float*)d_in[8];
    const float* w2  = (const float*)d_in[9];
    const float* b2  = (const float*)d_in[10];
    const float* wfc = (const float*)d_in[11];
    const float* bfc = (const float*)d_in[12];
    float* out = (float*)d_out;
    const int V = in_sizes[0];

    float* ws = (float*)d_ws;
    size_t off = 0;
    float* h    = ws + off; off += (size_t)V;
    float* f1   = ws + off; off += (size_t)V * 32;
    float* h2   = ws + off; off += (size_t)V * 32;
    float* f2   = ws + off; off += (size_t)V * 64;
    float* w2t  = ws + off; off += 3 * 32 * 64;
    short* wBh  = (short*)(ws + off); off += 32768 / 2;   // 32768 shorts
    short* wBm  = (short*)(ws + off); off += 32768 / 2;
    short* wBl  = (short*)(ws + off); off += 32768 / 2;

    k_prep<<<(32768 + 6144 + 255) / 256, 256, 0, stream>>>(wfc, w2, wBh, wBm, wBl, w2t);
    kA<<<(V * 32 + 255) / 256, 256, 0, stream>>>(vp, nb1, wv1, bv1, h, V);
    kB<<<(V * 32 + 255) / 256, 256, 0, stream>>>(h, w1, b1, f1, V);
    kC<<<(V + 7) / 8, 256, 0, stream>>>(f1, nb2, wv2, bv2, h2, V);
    kD<<<(V + 31) / 32, 256, 0, stream>>>(h2, w2t, b2, f2, V);
    kE<<<V / 32, 256, 0, stream>>>(f2, wBh, wBm, wBl, bfc, out, V);
}